// Round 2
// baseline (4751.875 us; speedup 1.0000x reference)
//
#include <hip/hip_runtime.h>
#include <hip/hip_bf16.h>
#include <math.h>

typedef __hip_bfloat16 bf16;
typedef short s16x8 __attribute__((ext_vector_type(8)));
typedef float f32x4 __attribute__((ext_vector_type(4)));

#define M_TOK 2048
#define DD    512
#define LSEQ  1024
#define PW    1088   /* 2D + R + 2N */
#define NST   16
#define RR    32
#define DFFW  2048

__device__ __forceinline__ float bf2f(bf16 v) { return __bfloat162float(v); }
__device__ __forceinline__ float siluf(float x) { return x / (1.f + expf(-x)); }

// ---------------- time embedding MLP (tiny, B=2) ----------------
__global__ __launch_bounds__(256) void k_time_embed(
    const int* __restrict__ t, const float* __restrict__ w1, const float* __restrict__ b1,
    const float* __restrict__ w2, const float* __restrict__ b2, float* __restrict__ te)
{
  __shared__ float emb[512];
  __shared__ float h1[2048];
  int b = blockIdx.x, tid = threadIdx.x;
  float tv = (float)t[b];
  {
    float f = expf((float)tid * (-9.210340371976184f / 255.f));
    float e = tv * f;
    emb[tid] = sinf(e);
    emb[tid + 256] = cosf(e);
  }
  __syncthreads();
  for (int j = tid; j < 2048; j += 256) {
    const float* wr = w1 + (size_t)j * 512;
    float s = b1[j];
    for (int k = 0; k < 512; ++k) s += wr[k] * emb[k];
    h1[j] = siluf(s);
  }
  __syncthreads();
  for (int d = tid; d < 512; d += 256) {
    const float* wr = w2 + (size_t)d * 2048;
    float s = b2[d];
    for (int k = 0; k < 2048; ++k) s += wr[k] * h1[k];
    te[b * 512 + d] = s;
  }
}

// ---------------- token embed + time embed add ----------------
__global__ __launch_bounds__(256) void k_embed(
    const int* __restrict__ x_t, const float* __restrict__ tok,
    const float* __restrict__ te, float* __restrict__ x)
{
  int m = blockIdx.x;              // 0..2047
  int b = m >> 10;
  int row = x_t[m];
  const float* src = tok + (size_t)row * DD;
  for (int d = threadIdx.x; d < DD; d += 256)
    x[(size_t)m * DD + d] = src[d] + te[b * DD + d];
}

// ---------------- LayerNorm (row of 512) -> bf16 ----------------
__global__ __launch_bounds__(256) void k_layernorm(
    const float* __restrict__ x, const float* __restrict__ g, const float* __restrict__ bb,
    bf16* __restrict__ out)
{
  int m = blockIdx.x;
  const float* xr = x + (size_t)m * DD;
  float2 v = ((const float2*)xr)[threadIdx.x];
  float s = v.x + v.y, ss = v.x * v.x + v.y * v.y;
  for (int o = 32; o; o >>= 1) { s += __shfl_down(s, o); ss += __shfl_down(ss, o); }
  __shared__ float ps[4], pss[4];
  int wave = threadIdx.x >> 6, lane = threadIdx.x & 63;
  if (!lane) { ps[wave] = s; pss[wave] = ss; }
  __syncthreads();
  s = ps[0] + ps[1] + ps[2] + ps[3];
  ss = pss[0] + pss[1] + pss[2] + pss[3];
  float mu = s * (1.f / DD);
  float var = ss * (1.f / DD) - mu * mu;
  float inv = rsqrtf(var + 1e-5f);
  int d = threadIdx.x * 2;
  out[(size_t)m * DD + d]     = __float2bfloat16((v.x - mu) * inv * g[d]     + bb[d]);
  out[(size_t)m * DD + d + 1] = __float2bfloat16((v.y - mu) * inv * g[d + 1] + bb[d + 1]);
}

// ---------------- depthwise causal conv + silu, and dt = softplus(dtu@Wdt^T+b) ----------------
__global__ __launch_bounds__(256) void k_conv_dt(
    const float* __restrict__ proj, const float* __restrict__ convw,
    const float* __restrict__ dtw, const float* __restrict__ dtb,
    float* __restrict__ u, float* __restrict__ dt)
{
  int m = blockIdx.x >> 1;
  int d = ((blockIdx.x & 1) << 8) + threadIdx.x;
  int b = m >> 10, l = m & 1023;
  __shared__ float dtu[RR];
  if (threadIdx.x < RR) dtu[threadIdx.x] = proj[(size_t)m * PW + 2 * DD + threadIdx.x];
  __syncthreads();
  float c = 0.f;
#pragma unroll
  for (int j = 0; j < 4; ++j) {
    int ll = l - 3 + j;
    if (ll >= 0) c += proj[(size_t)(b * LSEQ + ll) * PW + d] * convw[d * 4 + j];
  }
  u[(size_t)m * DD + d] = siluf(c);
  float s = dtb[d];
  const float* wr = dtw + (size_t)d * RR;
#pragma unroll
  for (int r = 0; r < RR; ++r) s += dtu[r] * wr[r];
  dt[(size_t)m * DD + d] = (s > 0.f) ? (s + log1pf(expf(-s))) : log1pf(expf(s));
}

// ---------------- sequential SSM scan (one thread per (b,d) chain) ----------------
__global__ __launch_bounds__(64) void k_scan(
    const float* __restrict__ proj, const float* __restrict__ u,
    const float* __restrict__ dt, float* __restrict__ y)
{
  int b = blockIdx.x >> 3;
  int d = ((blockIdx.x & 7) << 6) + threadIdx.x;
  float h[NST];
#pragma unroll
  for (int n = 0; n < NST; ++n) h[n] = 0.f;
  const float invn[NST] = {
    -1.f/1, -1.f/2, -1.f/3, -1.f/4, -1.f/5, -1.f/6, -1.f/7, -1.f/8,
    -1.f/9, -1.f/10, -1.f/11, -1.f/12, -1.f/13, -1.f/14, -1.f/15, -1.f/16 };
  for (int l = 0; l < LSEQ; ++l) {
    size_t m = (size_t)b * LSEQ + l;
    float dtv = dt[m * DD + d];
    float uv  = u[m * DD + d];
    float e1 = expf(-dtv);
    const float* bp = proj + m * PW + 2 * DD + RR;
    const float* cp = bp + NST;
    float a = 1.f, acc = 0.f;
#pragma unroll
    for (int n = 0; n < NST; ++n) {
      a *= e1;                                    // exp(-dt*(n+1))
      float bu = (a - 1.f) * invn[n] * bp[n] * uv;
      h[n] = a * h[n] + bu;
      acc += cp[n] * h[n];
    }
    y[m * DD + d] = acc;
  }
}

// ---------------- gate: (y + u*Dp) * silu(z) -> bf16 ----------------
__global__ __launch_bounds__(256) void k_gate(
    const float* __restrict__ y, const float* __restrict__ u,
    const float* __restrict__ proj, const float* __restrict__ Dp, bf16* __restrict__ out)
{
  int idx = blockIdx.x * 256 + threadIdx.x;     // M*D
  int m = idx >> 9, d = idx & 511;
  float z = proj[(size_t)m * PW + DD + d];
  float v = (y[idx] + u[idx] * Dp[d]) * siluf(z);
  out[idx] = __float2bfloat16(v);
}

// ---------------- generic MFMA GEMM: C[m,n] = sum_k A[m,k]*B[n,k] (+epilogue) ----------------
// A: bf16 [M,K] row-major (internal activations); B: f32 [N,K] row-major (weights),
// converted to bf16 while staging to LDS. M multiple of 128, K multiple of 32.
template<int ACT, bool BF16OUT, bool RES, bool BIAS>
__global__ __launch_bounds__(256) void gemm_abt(
    const bf16* __restrict__ A, const float* __restrict__ B,
    const float* __restrict__ bias, const float* __restrict__ res,
    void* __restrict__ Cout, int N, int K)
{
  __shared__ bf16 sA[128][32];
  __shared__ bf16 sB[128][32];
  int bn = blockIdx.x * 128;
  int bm = blockIdx.y * 128;
  int tid = threadIdx.x;
  int wave = tid >> 6, lane = tid & 63;
  int wm = (wave >> 1) << 6, wn = (wave & 1) << 6;
  int r = lane & 15, q = lane >> 4;
  int ldr = tid >> 2;
  int ldc = (tid & 3) << 3;

  f32x4 acc[4][4];
#pragma unroll
  for (int i = 0; i < 4; ++i)
#pragma unroll
    for (int j = 0; j < 4; ++j) acc[i][j] = (f32x4){0.f, 0.f, 0.f, 0.f};

  for (int k0 = 0; k0 < K; k0 += 32) {
#pragma unroll
    for (int h = 0; h < 2; ++h) {
      int row = ldr + (h << 6);
      *(s16x8*)&sA[row][ldc] = *(const s16x8*)(A + (size_t)(bm + row) * K + k0 + ldc);
      int nrow = bn + row;
      f32x4 b0 = {0.f,0.f,0.f,0.f}, b1 = {0.f,0.f,0.f,0.f};
      if (nrow < N) {
        const float* src = B + (size_t)nrow * K + k0 + ldc;
        b0 = *(const f32x4*)src;
        b1 = *(const f32x4*)(src + 4);
      }
      bf16* dst = &sB[row][ldc];
      dst[0] = __float2bfloat16(b0[0]); dst[1] = __float2bfloat16(b0[1]);
      dst[2] = __float2bfloat16(b0[2]); dst[3] = __float2bfloat16(b0[3]);
      dst[4] = __float2bfloat16(b1[0]); dst[5] = __float2bfloat16(b1[1]);
      dst[6] = __float2bfloat16(b1[2]); dst[7] = __float2bfloat16(b1[3]);
    }
    __syncthreads();
    s16x8 af[4], bg[4];
#pragma unroll
    for (int i = 0; i < 4; ++i) af[i] = *(s16x8*)&sA[wm + i * 16 + r][q << 3];
#pragma unroll
    for (int j = 0; j < 4; ++j) bg[j] = *(s16x8*)&sB[wn + j * 16 + r][q << 3];
#pragma unroll
    for (int i = 0; i < 4; ++i)
#pragma unroll
      for (int j = 0; j < 4; ++j)
        acc[i][j] = __builtin_amdgcn_mfma_f32_16x16x32_bf16(af[i], bg[j], acc[i][j], 0, 0, 0);
    __syncthreads();
  }

#pragma unroll
  for (int i = 0; i < 4; ++i)
#pragma unroll
    for (int j = 0; j < 4; ++j) {
      int n = bn + wn + j * 16 + r;
      if (n >= N) continue;
#pragma unroll
      for (int e = 0; e < 4; ++e) {
        int m = bm + wm + i * 16 + (q << 2) + e;
        float v = acc[i][j][e];
        if (BIAS) v += bias[n];
        if (ACT == 1) v = 0.5f * v * (1.f + erff(v * 0.70710678118f));  // exact GELU
        if (RES) v += res[(size_t)m * N + n];
        if (BF16OUT) ((bf16*)Cout)[(size_t)m * N + n] = __float2bfloat16(v);
        else         ((float*)Cout)[(size_t)m * N + n] = v;
      }
    }
}

// ---------------- launch ----------------
extern "C" void kernel_launch(void* const* d_in, const int* in_sizes, int n_in,
                              void* d_out, int out_size, void* d_ws, size_t ws_size,
                              hipStream_t stream) {
  const int*   x_t     = (const int*)d_in[0];
  const int*   t       = (const int*)d_in[1];
  const float* tok_emb = (const float*)d_in[2];
  const float* tmlp_w1 = (const float*)d_in[3];
  const float* tmlp_b1 = (const float*)d_in[4];
  const float* tmlp_w2 = (const float*)d_in[5];
  const float* tmlp_b2 = (const float*)d_in[6];
  const float* ln1_g   = (const float*)d_in[7];
  const float* ln1_b   = (const float*)d_in[8];
  const float* in_w    = (const float*)d_in[9];
  const float* conv_w  = (const float*)d_in[10];
  const float* dt_w    = (const float*)d_in[11];
  const float* dt_b    = (const float*)d_in[12];
  const float* D_p     = (const float*)d_in[13];
  const float* out_w   = (const float*)d_in[14];
  const float* ln2_g   = (const float*)d_in[15];
  const float* ln2_b   = (const float*)d_in[16];
  const float* mlp_w1  = (const float*)d_in[17];
  const float* mlp_b1  = (const float*)d_in[18];
  const float* mlp_w2  = (const float*)d_in[19];
  const float* mlp_b2  = (const float*)d_in[20];
  const float* lno_g   = (const float*)d_in[21];
  const float* lno_b   = (const float*)d_in[22];
  const float* head_w  = (const float*)d_in[23];
  const float* head_b  = (const float*)d_in[24];

  char* w = (char*)d_ws;
  float* te    = (float*)w;  w += 4096;
  float* x     = (float*)w;  w += (size_t)M_TOK * DD * 4;      // residual, f32
  bf16*  aIn   = (bf16*)w;   w += (size_t)M_TOK * DD * 2;      // bf16 GEMM A inputs
  float* proj  = (float*)w;  w += (size_t)M_TOK * PW * 4;      // in-proj out (f32); aliased by mlp hidden
  float* ubuf  = (float*)w;  w += (size_t)M_TOK * DD * 4;
  float* dtbuf = (float*)w;  w += (size_t)M_TOK * DD * 4;
  float* ybuf  = (float*)w;  w += (size_t)M_TOK * DD * 4;
  bf16*  gbuf  = (bf16*)proj;                                  // mlp hidden bf16 [M,2048] (8.4MB <= 8.9MB)

  k_time_embed<<<2, 256, 0, stream>>>(t, tmlp_w1, tmlp_b1, tmlp_w2, tmlp_b2, te);
  k_embed<<<M_TOK, 256, 0, stream>>>(x_t, tok_emb, te, x);

  for (int i = 0; i < 6; ++i) {
    const float* inw_i  = in_w   + (size_t)i * PW * DD;
    const float* cw_i   = conv_w + (size_t)i * DD * 4;
    const float* dtw_i  = dt_w   + (size_t)i * DD * RR;
    const float* dtb_i  = dt_b   + (size_t)i * DD;
    const float* dp_i   = D_p    + (size_t)i * DD;
    const float* ow_i   = out_w  + (size_t)i * DD * DD;
    const float* m1_i   = mlp_w1 + (size_t)i * DFFW * DD;
    const float* m1b_i  = mlp_b1 + (size_t)i * DFFW;
    const float* m2_i   = mlp_w2 + (size_t)i * DD * DFFW;
    const float* m2b_i  = mlp_b2 + (size_t)i * DD;

    k_layernorm<<<M_TOK, 256, 0, stream>>>(x, ln1_g + i * DD, ln1_b + i * DD, aIn);
    gemm_abt<0,false,false,false><<<dim3((PW + 127) / 128, M_TOK / 128), 256, 0, stream>>>(
        aIn, inw_i, nullptr, nullptr, proj, PW, DD);
    k_conv_dt<<<M_TOK * 2, 256, 0, stream>>>(proj, cw_i, dtw_i, dtb_i, ubuf, dtbuf);
    k_scan<<<16, 64, 0, stream>>>(proj, ubuf, dtbuf, ybuf);
    k_gate<<<M_TOK * DD / 256, 256, 0, stream>>>(ybuf, ubuf, proj, dp_i, aIn);
    gemm_abt<0,false,true,false><<<dim3(DD / 128, M_TOK / 128), 256, 0, stream>>>(
        aIn, ow_i, nullptr, x, x, DD, DD);
    k_layernorm<<<M_TOK, 256, 0, stream>>>(x, ln2_g + i * DD, ln2_b + i * DD, aIn);
    gemm_abt<1,true,false,true><<<dim3(DFFW / 128, M_TOK / 128), 256, 0, stream>>>(
        aIn, m1_i, m1b_i, nullptr, gbuf, DFFW, DD);
    gemm_abt<0,false,true,true><<<dim3(DD / 128, M_TOK / 128), 256, 0, stream>>>(
        gbuf, m2_i, m2b_i, x, x, DD, DFFW);
  }

  k_layernorm<<<M_TOK, 256, 0, stream>>>(x, lno_g, lno_b, aIn);
  gemm_abt<0,false,false,true><<<dim3((50000 + 127) / 128, M_TOK / 128), 256, 0, stream>>>(
      aIn, head_w, head_b, nullptr, d_out, 50000, DD);
}

// Round 3
// 2213.422 us; speedup vs baseline: 2.1468x; 2.1468x over previous
//
#include <hip/hip_runtime.h>
#include <hip/hip_bf16.h>
#include <math.h>

typedef __hip_bfloat16 bf16;
typedef short s16x8 __attribute__((ext_vector_type(8)));
typedef float f32x4 __attribute__((ext_vector_type(4)));

#define M_TOK 2048
#define DD    512
#define LSEQ  1024
#define PW    1088   /* 2D + R + 2N */
#define NST   16
#define RR    32
#define DFFW  2048
#define NCH   64     /* chunks per sequence */
#define CH    16     /* chunk length (NCH*CH == LSEQ) */

__device__ __forceinline__ float bf2f(bf16 v) { return __bfloat162float(v); }
__device__ __forceinline__ float siluf(float x) { return x / (1.f + expf(-x)); }

__constant__ float c_invn[NST] = {
  -1.f/1, -1.f/2, -1.f/3, -1.f/4, -1.f/5, -1.f/6, -1.f/7, -1.f/8,
  -1.f/9, -1.f/10, -1.f/11, -1.f/12, -1.f/13, -1.f/14, -1.f/15, -1.f/16 };

// ---------------- time embedding MLP (tiny, B=2) ----------------
__global__ __launch_bounds__(256) void k_time_embed(
    const int* __restrict__ t, const float* __restrict__ w1, const float* __restrict__ b1,
    const float* __restrict__ w2, const float* __restrict__ b2, float* __restrict__ te)
{
  __shared__ float emb[512];
  __shared__ float h1[2048];
  int b = blockIdx.x, tid = threadIdx.x;
  float tv = (float)t[b];
  {
    float f = expf((float)tid * (-9.210340371976184f / 255.f));
    float e = tv * f;
    emb[tid] = sinf(e);
    emb[tid + 256] = cosf(e);
  }
  __syncthreads();
  for (int j = tid; j < 2048; j += 256) {
    const float* wr = w1 + (size_t)j * 512;
    float s = b1[j];
    for (int k = 0; k < 512; ++k) s += wr[k] * emb[k];
    h1[j] = siluf(s);
  }
  __syncthreads();
  for (int d = tid; d < 512; d += 256) {
    const float* wr = w2 + (size_t)d * 2048;
    float s = b2[d];
    for (int k = 0; k < 2048; ++k) s += wr[k] * h1[k];
    te[b * 512 + d] = s;
  }
}

// ---------------- token embed + time embed add ----------------
__global__ __launch_bounds__(256) void k_embed(
    const int* __restrict__ x_t, const float* __restrict__ tok,
    const float* __restrict__ te, float* __restrict__ x)
{
  int m = blockIdx.x;              // 0..2047
  int b = m >> 10;
  int row = x_t[m];
  const float* src = tok + (size_t)row * DD;
  for (int d = threadIdx.x; d < DD; d += 256)
    x[(size_t)m * DD + d] = src[d] + te[b * DD + d];
}

// ---------------- LayerNorm (row of 512) -> bf16 ----------------
__global__ __launch_bounds__(256) void k_layernorm(
    const float* __restrict__ x, const float* __restrict__ g, const float* __restrict__ bb,
    bf16* __restrict__ out)
{
  int m = blockIdx.x;
  const float* xr = x + (size_t)m * DD;
  float2 v = ((const float2*)xr)[threadIdx.x];
  float s = v.x + v.y, ss = v.x * v.x + v.y * v.y;
  for (int o = 32; o; o >>= 1) { s += __shfl_down(s, o); ss += __shfl_down(ss, o); }
  __shared__ float ps[4], pss[4];
  int wave = threadIdx.x >> 6, lane = threadIdx.x & 63;
  if (!lane) { ps[wave] = s; pss[wave] = ss; }
  __syncthreads();
  s = ps[0] + ps[1] + ps[2] + ps[3];
  ss = pss[0] + pss[1] + pss[2] + pss[3];
  float mu = s * (1.f / DD);
  float var = ss * (1.f / DD) - mu * mu;
  float inv = rsqrtf(var + 1e-5f);
  int d = threadIdx.x * 2;
  out[(size_t)m * DD + d]     = __float2bfloat16((v.x - mu) * inv * g[d]     + bb[d]);
  out[(size_t)m * DD + d + 1] = __float2bfloat16((v.y - mu) * inv * g[d + 1] + bb[d + 1]);
}

// ---------------- depthwise causal conv + silu, and dt = softplus(dtu@Wdt^T+b) ----------------
__global__ __launch_bounds__(256) void k_conv_dt(
    const float* __restrict__ proj, const float* __restrict__ convw,
    const float* __restrict__ dtw, const float* __restrict__ dtb,
    float* __restrict__ u, float* __restrict__ dt)
{
  int m = blockIdx.x >> 1;
  int d = ((blockIdx.x & 1) << 8) + threadIdx.x;
  int b = m >> 10, l = m & 1023;
  __shared__ float dtu[RR];
  if (threadIdx.x < RR) dtu[threadIdx.x] = proj[(size_t)m * PW + 2 * DD + threadIdx.x];
  __syncthreads();
  float c = 0.f;
#pragma unroll
  for (int j = 0; j < 4; ++j) {
    int ll = l - 3 + j;
    if (ll >= 0) c += proj[(size_t)(b * LSEQ + ll) * PW + d] * convw[d * 4 + j];
  }
  u[(size_t)m * DD + d] = siluf(c);
  float s = dtb[d];
  const float* wr = dtw + (size_t)d * RR;
#pragma unroll
  for (int r = 0; r < RR; ++r) s += dtu[r] * wr[r];
  dt[(size_t)m * DD + d] = (s > 0.f) ? (s + log1pf(expf(-s))) : log1pf(expf(s));
}

// ---------------- scan pass 1: local chunk scans ----------------
// grid (4, NCH, B), 128 threads. Writes yloc, E[l]=exp(-cumsum dt), and per-chunk
// Aprod[n]=Ec^{n+1}, hend[n] in layout ((b*NCH+c)*NST+n)*DD+d (coalesced over d).
__global__ __launch_bounds__(128) void k_scan1(
    const float* __restrict__ proj, const float* __restrict__ u,
    const float* __restrict__ dt, float* __restrict__ yloc,
    float* __restrict__ Ebuf, float* __restrict__ Aprod, float* __restrict__ hend)
{
  int d = (blockIdx.x << 7) + threadIdx.x;
  int c = blockIdx.y, b = blockIdx.z;
  int m0 = b * LSEQ + c * CH;
  __shared__ float sBC[CH][32];   // [l][0..15]=B, [16..31]=C
  for (int idx = threadIdx.x; idx < CH * 32; idx += 128)
    sBC[idx >> 5][idx & 31] = proj[(size_t)(m0 + (idx >> 5)) * PW + 2 * DD + RR + (idx & 31)];
  __syncthreads();
  float h[NST];
#pragma unroll
  for (int n = 0; n < NST; ++n) h[n] = 0.f;
  float S = 0.f;
  for (int l = 0; l < CH; ++l) {
    size_t m = (size_t)(m0 + l);
    float dtv = dt[m * DD + d];
    float uv  = u[m * DD + d];
    float e1 = expf(-dtv);
    S += dtv;
    Ebuf[m * DD + d] = expf(-S);
    float p = 1.f, acc = 0.f;
#pragma unroll
    for (int n = 0; n < NST; ++n) {
      p *= e1;                                    // e1^(n+1)
      float bu = (p - 1.f) * c_invn[n] * sBC[l][n] * uv;
      h[n] = p * h[n] + bu;
      acc += sBC[l][16 + n] * h[n];
    }
    yloc[m * DD + d] = acc;
  }
  float Ec = expf(-S);
  float p = 1.f;
  size_t base = ((size_t)(b * NCH + c) * NST) * DD + d;
#pragma unroll
  for (int n = 0; n < NST; ++n) {
    p *= Ec;
    Aprod[base + (size_t)n * DD] = p;
    hend [base + (size_t)n * DD] = h[n];
  }
}

// ---------------- scan pass 2: prefix combine over chunks ----------------
// one thread per (b,n,d): h0[c] = state entering chunk c.
__global__ __launch_bounds__(256) void k_scan2(
    const float* __restrict__ Aprod, const float* __restrict__ hend, float* __restrict__ h0)
{
  int idx = blockIdx.x * 256 + threadIdx.x;   // [b][n][d]
  int d = idx & 511;
  int n = (idx >> 9) & 15;
  int b = idx >> 13;
  float h = 0.f;
  for (int c = 0; c < NCH; ++c) {
    size_t o = ((size_t)((b * NCH + c) * NST + n)) * DD + d;
    h0[o] = h;
    h = Aprod[o] * h + hend[o];
  }
}

// ---------------- scan pass 3 + gate: y = yloc + C·(E^{n+1} ⊙ h0); out=(y+u*Dp)*silu(z) ----------------
__global__ __launch_bounds__(128) void k_scan3(
    const float* __restrict__ proj, const float* __restrict__ u,
    const float* __restrict__ yloc, const float* __restrict__ Ebuf,
    const float* __restrict__ h0, const float* __restrict__ Dp, bf16* __restrict__ out)
{
  int d = (blockIdx.x << 7) + threadIdx.x;
  int c = blockIdx.y, b = blockIdx.z;
  int m0 = b * LSEQ + c * CH;
  __shared__ float sC[CH][NST];
  for (int idx = threadIdx.x; idx < CH * NST; idx += 128)
    sC[idx >> 4][idx & 15] = proj[(size_t)(m0 + (idx >> 4)) * PW + 2 * DD + RR + NST + (idx & 15)];
  __syncthreads();
  float hh[NST];
  size_t base = ((size_t)(b * NCH + c) * NST) * DD + d;
#pragma unroll
  for (int n = 0; n < NST; ++n) hh[n] = h0[base + (size_t)n * DD];
  float dpv = Dp[d];
  for (int l = 0; l < CH; ++l) {
    size_t m = (size_t)(m0 + l);
    float E = Ebuf[m * DD + d];
    float p = 1.f, corr = 0.f;
#pragma unroll
    for (int n = 0; n < NST; ++n) {
      p *= E;                                     // E^(n+1)
      corr += sC[l][n] * p * hh[n];
    }
    float y = yloc[m * DD + d] + corr;
    float z = proj[m * PW + DD + d];
    float v = (y + u[m * DD + d] * dpv) * siluf(z);
    out[m * DD + d] = __float2bfloat16(v);
  }
}

// ---------------- generic MFMA GEMM: C[m,n] = sum_k A[m,k]*B[n,k] (+epilogue) ----------------
template<int ACT, bool BF16OUT, bool RES, bool BIAS>
__global__ __launch_bounds__(256) void gemm_abt(
    const bf16* __restrict__ A, const float* __restrict__ B,
    const float* __restrict__ bias, const float* __restrict__ res,
    void* __restrict__ Cout, int N, int K)
{
  __shared__ bf16 sA[128][32];
  __shared__ bf16 sB[128][32];
  int bn = blockIdx.x * 128;
  int bm = blockIdx.y * 128;
  int tid = threadIdx.x;
  int wave = tid >> 6, lane = tid & 63;
  int wm = (wave >> 1) << 6, wn = (wave & 1) << 6;
  int r = lane & 15, q = lane >> 4;
  int ldr = tid >> 2;
  int ldc = (tid & 3) << 3;

  f32x4 acc[4][4];
#pragma unroll
  for (int i = 0; i < 4; ++i)
#pragma unroll
    for (int j = 0; j < 4; ++j) acc[i][j] = (f32x4){0.f, 0.f, 0.f, 0.f};

  for (int k0 = 0; k0 < K; k0 += 32) {
#pragma unroll
    for (int h = 0; h < 2; ++h) {
      int row = ldr + (h << 6);
      *(s16x8*)&sA[row][ldc] = *(const s16x8*)(A + (size_t)(bm + row) * K + k0 + ldc);
      int nrow = bn + row;
      f32x4 b0 = {0.f,0.f,0.f,0.f}, b1 = {0.f,0.f,0.f,0.f};
      if (nrow < N) {
        const float* src = B + (size_t)nrow * K + k0 + ldc;
        b0 = *(const f32x4*)src;
        b1 = *(const f32x4*)(src + 4);
      }
      bf16* dst = &sB[row][ldc];
      dst[0] = __float2bfloat16(b0[0]); dst[1] = __float2bfloat16(b0[1]);
      dst[2] = __float2bfloat16(b0[2]); dst[3] = __float2bfloat16(b0[3]);
      dst[4] = __float2bfloat16(b1[0]); dst[5] = __float2bfloat16(b1[1]);
      dst[6] = __float2bfloat16(b1[2]); dst[7] = __float2bfloat16(b1[3]);
    }
    __syncthreads();
    s16x8 af[4], bg[4];
#pragma unroll
    for (int i = 0; i < 4; ++i) af[i] = *(s16x8*)&sA[wm + i * 16 + r][q << 3];
#pragma unroll
    for (int j = 0; j < 4; ++j) bg[j] = *(s16x8*)&sB[wn + j * 16 + r][q << 3];
#pragma unroll
    for (int i = 0; i < 4; ++i)
#pragma unroll
      for (int j = 0; j < 4; ++j)
        acc[i][j] = __builtin_amdgcn_mfma_f32_16x16x32_bf16(af[i], bg[j], acc[i][j], 0, 0, 0);
    __syncthreads();
  }

#pragma unroll
  for (int i = 0; i < 4; ++i)
#pragma unroll
    for (int j = 0; j < 4; ++j) {
      int n = bn + wn + j * 16 + r;
      if (n >= N) continue;
#pragma unroll
      for (int e = 0; e < 4; ++e) {
        int m = bm + wm + i * 16 + (q << 2) + e;
        float v = acc[i][j][e];
        if (BIAS) v += bias[n];
        if (ACT == 1) v = 0.5f * v * (1.f + erff(v * 0.70710678118f));  // exact GELU
        if (RES) v += res[(size_t)m * N + n];
        if (BF16OUT) ((bf16*)Cout)[(size_t)m * N + n] = __float2bfloat16(v);
        else         ((float*)Cout)[(size_t)m * N + n] = v;
      }
    }
}

// ---------------- launch ----------------
extern "C" void kernel_launch(void* const* d_in, const int* in_sizes, int n_in,
                              void* d_out, int out_size, void* d_ws, size_t ws_size,
                              hipStream_t stream) {
  const int*   x_t     = (const int*)d_in[0];
  const int*   t       = (const int*)d_in[1];
  const float* tok_emb = (const float*)d_in[2];
  const float* tmlp_w1 = (const float*)d_in[3];
  const float* tmlp_b1 = (const float*)d_in[4];
  const float* tmlp_w2 = (const float*)d_in[5];
  const float* tmlp_b2 = (const float*)d_in[6];
  const float* ln1_g   = (const float*)d_in[7];
  const float* ln1_b   = (const float*)d_in[8];
  const float* in_w    = (const float*)d_in[9];
  const float* conv_w  = (const float*)d_in[10];
  const float* dt_w    = (const float*)d_in[11];
  const float* dt_b    = (const float*)d_in[12];
  const float* D_p     = (const float*)d_in[13];
  const float* out_w   = (const float*)d_in[14];
  const float* ln2_g   = (const float*)d_in[15];
  const float* ln2_b   = (const float*)d_in[16];
  const float* mlp_w1  = (const float*)d_in[17];
  const float* mlp_b1  = (const float*)d_in[18];
  const float* mlp_w2  = (const float*)d_in[19];
  const float* mlp_b2  = (const float*)d_in[20];
  const float* lno_g   = (const float*)d_in[21];
  const float* lno_b   = (const float*)d_in[22];
  const float* head_w  = (const float*)d_in[23];
  const float* head_b  = (const float*)d_in[24];

  char* w = (char*)d_ws;
  float* te    = (float*)w;  w += 4096;
  float* x     = (float*)w;  w += (size_t)M_TOK * DD * 4;      // residual, f32
  bf16*  aIn   = (bf16*)w;   w += (size_t)M_TOK * DD * 2;      // bf16 GEMM A inputs
  float* proj  = (float*)w;  w += (size_t)M_TOK * PW * 4;      // in-proj out (f32); aliased by mlp hidden
  float* ubuf  = (float*)w;  w += (size_t)M_TOK * DD * 4;
  float* dtbuf = (float*)w;  w += (size_t)M_TOK * DD * 4;
  float* ybuf  = (float*)w;  w += (size_t)M_TOK * DD * 4;      // yloc
  float* Ebuf  = (float*)w;  w += (size_t)M_TOK * DD * 4;
  float* Aprod = (float*)w;  w += (size_t)2 * NCH * NST * DD * 4;
  float* hend  = (float*)w;  w += (size_t)2 * NCH * NST * DD * 4;
  float* h0    = (float*)w;  w += (size_t)2 * NCH * NST * DD * 4;
  bf16*  gbuf  = (bf16*)proj;                                  // mlp hidden bf16 [M,2048]

  k_time_embed<<<2, 256, 0, stream>>>(t, tmlp_w1, tmlp_b1, tmlp_w2, tmlp_b2, te);
  k_embed<<<M_TOK, 256, 0, stream>>>(x_t, tok_emb, te, x);

  for (int i = 0; i < 6; ++i) {
    const float* inw_i  = in_w   + (size_t)i * PW * DD;
    const float* cw_i   = conv_w + (size_t)i * DD * 4;
    const float* dtw_i  = dt_w   + (size_t)i * DD * RR;
    const float* dtb_i  = dt_b   + (size_t)i * DD;
    const float* dp_i   = D_p    + (size_t)i * DD;
    const float* ow_i   = out_w  + (size_t)i * DD * DD;
    const float* m1_i   = mlp_w1 + (size_t)i * DFFW * DD;
    const float* m1b_i  = mlp_b1 + (size_t)i * DFFW;
    const float* m2_i   = mlp_w2 + (size_t)i * DD * DFFW;
    const float* m2b_i  = mlp_b2 + (size_t)i * DD;

    k_layernorm<<<M_TOK, 256, 0, stream>>>(x, ln1_g + i * DD, ln1_b + i * DD, aIn);
    gemm_abt<0,false,false,false><<<dim3((PW + 127) / 128, M_TOK / 128), 256, 0, stream>>>(
        aIn, inw_i, nullptr, nullptr, proj, PW, DD);
    k_conv_dt<<<M_TOK * 2, 256, 0, stream>>>(proj, cw_i, dtw_i, dtb_i, ubuf, dtbuf);
    k_scan1<<<dim3(4, NCH, 2), 128, 0, stream>>>(proj, ubuf, dtbuf, ybuf, Ebuf, Aprod, hend);
    k_scan2<<<2 * NST * DD / 256, 256, 0, stream>>>(Aprod, hend, h0);
    k_scan3<<<dim3(4, NCH, 2), 128, 0, stream>>>(proj, ubuf, ybuf, Ebuf, h0, dp_i, aIn);
    gemm_abt<0,false,true,false><<<dim3(DD / 128, M_TOK / 128), 256, 0, stream>>>(
        aIn, ow_i, nullptr, x, x, DD, DD);
    k_layernorm<<<M_TOK, 256, 0, stream>>>(x, ln2_g + i * DD, ln2_b + i * DD, aIn);
    gemm_abt<1,true,false,true><<<dim3(DFFW / 128, M_TOK / 128), 256, 0, stream>>>(
        aIn, m1_i, m1b_i, nullptr, gbuf, DFFW, DD);
    gemm_abt<0,false,true,true><<<dim3(DD / 128, M_TOK / 128), 256, 0, stream>>>(
        gbuf, m2_i, m2b_i, x, x, DD, DFFW);
  }

  k_layernorm<<<M_TOK, 256, 0, stream>>>(x, lno_g, lno_b, aIn);
  gemm_abt<0,false,false,true><<<dim3((50000 + 127) / 128, M_TOK / 128), 256, 0, stream>>>(
      aIn, head_w, head_b, nullptr, d_out, 50000, DD);
}

// Round 4
// 1602.275 us; speedup vs baseline: 2.9657x; 1.3814x over previous
//
#include <hip/hip_runtime.h>
#include <hip/hip_bf16.h>
#include <math.h>

typedef __hip_bfloat16 bf16;
typedef short s16x8 __attribute__((ext_vector_type(8)));
typedef float f32x4 __attribute__((ext_vector_type(4)));

#define M_TOK 2048
#define DD    512
#define LSEQ  1024
#define PW    1088   /* 2D + R + 2N */
#define NST   16
#define RR    32
#define DFFW  2048
#define NCH   64     /* chunks per sequence */
#define CH    16     /* chunk length (NCH*CH == LSEQ) */

__device__ __forceinline__ float bf2f(bf16 v) { return __bfloat162float(v); }
__device__ __forceinline__ float siluf(float x) { return x / (1.f + expf(-x)); }

__constant__ float c_invn[NST] = {
  -1.f/1, -1.f/2, -1.f/3, -1.f/4, -1.f/5, -1.f/6, -1.f/7, -1.f/8,
  -1.f/9, -1.f/10, -1.f/11, -1.f/12, -1.f/13, -1.f/14, -1.f/15, -1.f/16 };

// ---------------- time embedding MLP (tiny, B=2) ----------------
__global__ __launch_bounds__(256) void k_time_embed(
    const int* __restrict__ t, const float* __restrict__ w1, const float* __restrict__ b1,
    const float* __restrict__ w2, const float* __restrict__ b2, float* __restrict__ te)
{
  __shared__ float emb[512];
  __shared__ float h1[2048];
  int b = blockIdx.x, tid = threadIdx.x;
  float tv = (float)t[b];
  {
    float f = expf((float)tid * (-9.210340371976184f / 255.f));
    float e = tv * f;
    emb[tid] = sinf(e);
    emb[tid + 256] = cosf(e);
  }
  __syncthreads();
  for (int j = tid; j < 2048; j += 256) {
    const float* wr = w1 + (size_t)j * 512;
    float s = b1[j];
    for (int k = 0; k < 512; ++k) s += wr[k] * emb[k];
    h1[j] = siluf(s);
  }
  __syncthreads();
  for (int d = tid; d < 512; d += 256) {
    const float* wr = w2 + (size_t)d * 2048;
    float s = b2[d];
    for (int k = 0; k < 2048; ++k) s += wr[k] * h1[k];
    te[b * 512 + d] = s;
  }
}

// ---------------- token embed + time embed add ----------------
__global__ __launch_bounds__(256) void k_embed(
    const int* __restrict__ x_t, const float* __restrict__ tok,
    const float* __restrict__ te, float* __restrict__ x)
{
  int m = blockIdx.x;              // 0..2047
  int b = m >> 10;
  int row = x_t[m];
  const float* src = tok + (size_t)row * DD;
  for (int d = threadIdx.x; d < DD; d += 256)
    x[(size_t)m * DD + d] = src[d] + te[b * DD + d];
}

// ---------------- LayerNorm (row of 512) -> bf16 ----------------
__global__ __launch_bounds__(256) void k_layernorm(
    const float* __restrict__ x, const float* __restrict__ g, const float* __restrict__ bb,
    bf16* __restrict__ out)
{
  int m = blockIdx.x;
  const float* xr = x + (size_t)m * DD;
  float2 v = ((const float2*)xr)[threadIdx.x];
  float s = v.x + v.y, ss = v.x * v.x + v.y * v.y;
  for (int o = 32; o; o >>= 1) { s += __shfl_down(s, o); ss += __shfl_down(ss, o); }
  __shared__ float ps[4], pss[4];
  int wave = threadIdx.x >> 6, lane = threadIdx.x & 63;
  if (!lane) { ps[wave] = s; pss[wave] = ss; }
  __syncthreads();
  s = ps[0] + ps[1] + ps[2] + ps[3];
  ss = pss[0] + pss[1] + pss[2] + pss[3];
  float mu = s * (1.f / DD);
  float var = ss * (1.f / DD) - mu * mu;
  float inv = rsqrtf(var + 1e-5f);
  int d = threadIdx.x * 2;
  out[(size_t)m * DD + d]     = __float2bfloat16((v.x - mu) * inv * g[d]     + bb[d]);
  out[(size_t)m * DD + d + 1] = __float2bfloat16((v.y - mu) * inv * g[d + 1] + bb[d + 1]);
}

// ---------------- depthwise causal conv + silu, and dt = softplus(dtu@Wdt^T+b) ----------------
__global__ __launch_bounds__(256) void k_conv_dt(
    const float* __restrict__ proj, const float* __restrict__ convw,
    const float* __restrict__ dtw, const float* __restrict__ dtb,
    float* __restrict__ u, float* __restrict__ dt)
{
  int m = blockIdx.x >> 1;
  int d = ((blockIdx.x & 1) << 8) + threadIdx.x;
  int b = m >> 10, l = m & 1023;
  __shared__ float dtu[RR];
  if (threadIdx.x < RR) dtu[threadIdx.x] = proj[(size_t)m * PW + 2 * DD + threadIdx.x];
  __syncthreads();
  float c = 0.f;
#pragma unroll
  for (int j = 0; j < 4; ++j) {
    int ll = l - 3 + j;
    if (ll >= 0) c += proj[(size_t)(b * LSEQ + ll) * PW + d] * convw[d * 4 + j];
  }
  u[(size_t)m * DD + d] = siluf(c);
  float s = dtb[d];
  const float* wr = dtw + (size_t)d * RR;
#pragma unroll
  for (int r = 0; r < RR; ++r) s += dtu[r] * wr[r];
  dt[(size_t)m * DD + d] = (s > 0.f) ? (s + log1pf(expf(-s))) : log1pf(expf(s));
}

// ---------------- scan pass 1: local chunk scans ----------------
__global__ __launch_bounds__(128) void k_scan1(
    const float* __restrict__ proj, const float* __restrict__ u,
    const float* __restrict__ dt, float* __restrict__ yloc,
    float* __restrict__ Ebuf, float* __restrict__ Aprod, float* __restrict__ hend)
{
  int d = (blockIdx.x << 7) + threadIdx.x;
  int c = blockIdx.y, b = blockIdx.z;
  int m0 = b * LSEQ + c * CH;
  __shared__ float sBC[CH][32];   // [l][0..15]=B, [16..31]=C
  for (int idx = threadIdx.x; idx < CH * 32; idx += 128)
    sBC[idx >> 5][idx & 31] = proj[(size_t)(m0 + (idx >> 5)) * PW + 2 * DD + RR + (idx & 31)];
  __syncthreads();
  float h[NST];
#pragma unroll
  for (int n = 0; n < NST; ++n) h[n] = 0.f;
  float S = 0.f;
  for (int l = 0; l < CH; ++l) {
    size_t m = (size_t)(m0 + l);
    float dtv = dt[m * DD + d];
    float uv  = u[m * DD + d];
    float e1 = expf(-dtv);
    S += dtv;
    Ebuf[m * DD + d] = expf(-S);
    float p = 1.f, acc = 0.f;
#pragma unroll
    for (int n = 0; n < NST; ++n) {
      p *= e1;                                    // e1^(n+1)
      float bu = (p - 1.f) * c_invn[n] * sBC[l][n] * uv;
      h[n] = p * h[n] + bu;
      acc += sBC[l][16 + n] * h[n];
    }
    yloc[m * DD + d] = acc;
  }
  float Ec = expf(-S);
  float p = 1.f;
  size_t base = ((size_t)(b * NCH + c) * NST) * DD + d;
#pragma unroll
  for (int n = 0; n < NST; ++n) {
    p *= Ec;
    Aprod[base + (size_t)n * DD] = p;
    hend [base + (size_t)n * DD] = h[n];
  }
}

// ---------------- scan pass 2: prefix combine over chunks ----------------
__global__ __launch_bounds__(256) void k_scan2(
    const float* __restrict__ Aprod, const float* __restrict__ hend, float* __restrict__ h0)
{
  int idx = blockIdx.x * 256 + threadIdx.x;   // [b][n][d]
  int d = idx & 511;
  int n = (idx >> 9) & 15;
  int b = idx >> 13;
  float h = 0.f;
  for (int c = 0; c < NCH; ++c) {
    size_t o = ((size_t)((b * NCH + c) * NST + n)) * DD + d;
    h0[o] = h;
    h = Aprod[o] * h + hend[o];
  }
}

// ---------------- scan pass 3 + gate ----------------
__global__ __launch_bounds__(128) void k_scan3(
    const float* __restrict__ proj, const float* __restrict__ u,
    const float* __restrict__ yloc, const float* __restrict__ Ebuf,
    const float* __restrict__ h0, const float* __restrict__ Dp, bf16* __restrict__ out)
{
  int d = (blockIdx.x << 7) + threadIdx.x;
  int c = blockIdx.y, b = blockIdx.z;
  int m0 = b * LSEQ + c * CH;
  __shared__ float sC[CH][NST];
  for (int idx = threadIdx.x; idx < CH * NST; idx += 128)
    sC[idx >> 4][idx & 15] = proj[(size_t)(m0 + (idx >> 4)) * PW + 2 * DD + RR + NST + (idx & 15)];
  __syncthreads();
  float hh[NST];
  size_t base = ((size_t)(b * NCH + c) * NST) * DD + d;
#pragma unroll
  for (int n = 0; n < NST; ++n) hh[n] = h0[base + (size_t)n * DD];
  float dpv = Dp[d];
  for (int l = 0; l < CH; ++l) {
    size_t m = (size_t)(m0 + l);
    float E = Ebuf[m * DD + d];
    float p = 1.f, corr = 0.f;
#pragma unroll
    for (int n = 0; n < NST; ++n) {
      p *= E;                                     // E^(n+1)
      corr += sC[l][n] * p * hh[n];
    }
    float y = yloc[m * DD + d] + corr;
    float z = proj[m * PW + DD + d];
    float v = (y + u[m * DD + d] * dpv) * siluf(z);
    out[m * DD + d] = __float2bfloat16(v);
  }
}

// ---------------- 128x128 MFMA GEMM with 2-phase prefetch ----------------
// C[m,n] = sum_k A[m,k]*B[n,k]. A bf16 [M,K]; B f32 [N,K] (cvt to bf16 in staging).
// TRANS: grid.x = M-tiles (consecutive blocks share B panel -> L2 reuse).
template<int ACT, bool BF16OUT, bool RES, bool BIAS, bool TRANS>
__global__ __launch_bounds__(256) void gemm_abt(
    const bf16* __restrict__ A, const float* __restrict__ B,
    const float* __restrict__ bias, const float* __restrict__ res,
    void* __restrict__ Cout, int N, int K)
{
  __shared__ bf16 sA[128][40];   // +8 pad: row stride 80B = 20 banks -> conflict-free
  __shared__ bf16 sB[128][40];
  int bn = (TRANS ? blockIdx.y : blockIdx.x) * 128;
  int bm = (TRANS ? blockIdx.x : blockIdx.y) * 128;
  int tid = threadIdx.x;
  int wave = tid >> 6, lane = tid & 63;
  int wm = (wave >> 1) << 6, wn = (wave & 1) << 6;
  int r = lane & 15, q = lane >> 4;
  int ldr = tid >> 2;
  int ldc = (tid & 3) << 3;

  f32x4 acc[4][4];
#pragma unroll
  for (int i = 0; i < 4; ++i)
#pragma unroll
    for (int j = 0; j < 4; ++j) acc[i][j] = (f32x4){0.f, 0.f, 0.f, 0.f};

  s16x8 pa[2];
  f32x4 pb[2][2];
#define GLOAD(k0)                                                              \
  {                                                                            \
    _Pragma("unroll")                                                          \
    for (int h = 0; h < 2; ++h) {                                              \
      int row = ldr + (h << 6);                                                \
      pa[h] = *(const s16x8*)(A + (size_t)(bm + row) * K + (k0) + ldc);        \
      int nrow = bn + row;                                                     \
      if (nrow < N) {                                                          \
        const float* src = B + (size_t)nrow * K + (k0) + ldc;                  \
        pb[h][0] = *(const f32x4*)src;                                         \
        pb[h][1] = *(const f32x4*)(src + 4);                                   \
      } else {                                                                 \
        pb[h][0] = (f32x4){0.f,0.f,0.f,0.f};                                   \
        pb[h][1] = (f32x4){0.f,0.f,0.f,0.f};                                   \
      }                                                                        \
    }                                                                          \
  }

  GLOAD(0);
  for (int k0 = 0; k0 < K; k0 += 32) {
#pragma unroll
    for (int h = 0; h < 2; ++h) {
      int row = ldr + (h << 6);
      *(s16x8*)&sA[row][ldc] = pa[h];
      bf16* dst = &sB[row][ldc];
      dst[0] = __float2bfloat16(pb[h][0][0]); dst[1] = __float2bfloat16(pb[h][0][1]);
      dst[2] = __float2bfloat16(pb[h][0][2]); dst[3] = __float2bfloat16(pb[h][0][3]);
      dst[4] = __float2bfloat16(pb[h][1][0]); dst[5] = __float2bfloat16(pb[h][1][1]);
      dst[6] = __float2bfloat16(pb[h][1][2]); dst[7] = __float2bfloat16(pb[h][1][3]);
    }
    __syncthreads();
    if (k0 + 32 < K) GLOAD(k0 + 32);   // overlap next tile's HBM latency with MFMA
    s16x8 af[4], bg[4];
#pragma unroll
    for (int i = 0; i < 4; ++i) af[i] = *(s16x8*)&sA[wm + i * 16 + r][q << 3];
#pragma unroll
    for (int j = 0; j < 4; ++j) bg[j] = *(s16x8*)&sB[wn + j * 16 + r][q << 3];
#pragma unroll
    for (int i = 0; i < 4; ++i)
#pragma unroll
      for (int j = 0; j < 4; ++j)
        acc[i][j] = __builtin_amdgcn_mfma_f32_16x16x32_bf16(af[i], bg[j], acc[i][j], 0, 0, 0);
    __syncthreads();
  }
#undef GLOAD

#pragma unroll
  for (int i = 0; i < 4; ++i)
#pragma unroll
    for (int j = 0; j < 4; ++j) {
      int n = bn + wn + j * 16 + r;
      if (n >= N) continue;
#pragma unroll
      for (int e = 0; e < 4; ++e) {
        int m = bm + wm + i * 16 + (q << 2) + e;
        float v = acc[i][j][e];
        if (BIAS) v += bias[n];
        if (ACT == 1) v = 0.5f * v * (1.f + erff(v * 0.70710678118f));  // exact GELU
        if (RES) v += res[(size_t)m * N + n];
        if (BF16OUT) ((bf16*)Cout)[(size_t)m * N + n] = __float2bfloat16(v);
        else         ((float*)Cout)[(size_t)m * N + n] = v;
      }
    }
}

// ---------------- 64x64 MFMA GEMM (more blocks for small N) ----------------
// Requires M%64==0, N%64==0, K%32==0. grid (N/64, M/64).
template<int ACT, bool BF16OUT, bool RES, bool BIAS>
__global__ __launch_bounds__(256) void gemm64(
    const bf16* __restrict__ A, const float* __restrict__ B,
    const float* __restrict__ bias, const float* __restrict__ res,
    void* __restrict__ Cout, int N, int K)
{
  __shared__ bf16 sA[64][40];
  __shared__ bf16 sB[64][40];
  int bn = blockIdx.x * 64;
  int bm = blockIdx.y * 64;
  int tid = threadIdx.x;
  int wave = tid >> 6, lane = tid & 63;
  int wm = (wave >> 1) << 5, wn = (wave & 1) << 5;
  int r = lane & 15, q = lane >> 4;
  int ldr = tid >> 2;
  int ldc = (tid & 3) << 3;

  f32x4 acc[2][2];
#pragma unroll
  for (int i = 0; i < 2; ++i)
#pragma unroll
    for (int j = 0; j < 2; ++j) acc[i][j] = (f32x4){0.f, 0.f, 0.f, 0.f};

  s16x8 pa;
  f32x4 pb[2];
#define GLOAD64(k0)                                                            \
  {                                                                            \
    pa = *(const s16x8*)(A + (size_t)(bm + ldr) * K + (k0) + ldc);             \
    const float* src = B + (size_t)(bn + ldr) * K + (k0) + ldc;                \
    pb[0] = *(const f32x4*)src;                                                \
    pb[1] = *(const f32x4*)(src + 4);                                          \
  }

  GLOAD64(0);
  for (int k0 = 0; k0 < K; k0 += 32) {
    *(s16x8*)&sA[ldr][ldc] = pa;
    {
      bf16* dst = &sB[ldr][ldc];
      dst[0] = __float2bfloat16(pb[0][0]); dst[1] = __float2bfloat16(pb[0][1]);
      dst[2] = __float2bfloat16(pb[0][2]); dst[3] = __float2bfloat16(pb[0][3]);
      dst[4] = __float2bfloat16(pb[1][0]); dst[5] = __float2bfloat16(pb[1][1]);
      dst[6] = __float2bfloat16(pb[1][2]); dst[7] = __float2bfloat16(pb[1][3]);
    }
    __syncthreads();
    if (k0 + 32 < K) GLOAD64(k0 + 32);
    s16x8 af[2], bg[2];
#pragma unroll
    for (int i = 0; i < 2; ++i) af[i] = *(s16x8*)&sA[wm + i * 16 + r][q << 3];
#pragma unroll
    for (int j = 0; j < 2; ++j) bg[j] = *(s16x8*)&sB[wn + j * 16 + r][q << 3];
#pragma unroll
    for (int i = 0; i < 2; ++i)
#pragma unroll
      for (int j = 0; j < 2; ++j)
        acc[i][j] = __builtin_amdgcn_mfma_f32_16x16x32_bf16(af[i], bg[j], acc[i][j], 0, 0, 0);
    __syncthreads();
  }
#undef GLOAD64

#pragma unroll
  for (int i = 0; i < 2; ++i)
#pragma unroll
    for (int j = 0; j < 2; ++j) {
      int n = bn + wn + j * 16 + r;
#pragma unroll
      for (int e = 0; e < 4; ++e) {
        int m = bm + wm + i * 16 + (q << 2) + e;
        float v = acc[i][j][e];
        if (BIAS) v += bias[n];
        if (ACT == 1) v = 0.5f * v * (1.f + erff(v * 0.70710678118f));
        if (RES) v += res[(size_t)m * N + n];
        if (BF16OUT) ((bf16*)Cout)[(size_t)m * N + n] = __float2bfloat16(v);
        else         ((float*)Cout)[(size_t)m * N + n] = v;
      }
    }
}

// ---------------- launch ----------------
extern "C" void kernel_launch(void* const* d_in, const int* in_sizes, int n_in,
                              void* d_out, int out_size, void* d_ws, size_t ws_size,
                              hipStream_t stream) {
  const int*   x_t     = (const int*)d_in[0];
  const int*   t       = (const int*)d_in[1];
  const float* tok_emb = (const float*)d_in[2];
  const float* tmlp_w1 = (const float*)d_in[3];
  const float* tmlp_b1 = (const float*)d_in[4];
  const float* tmlp_w2 = (const float*)d_in[5];
  const float* tmlp_b2 = (const float*)d_in[6];
  const float* ln1_g   = (const float*)d_in[7];
  const float* ln1_b   = (const float*)d_in[8];
  const float* in_w    = (const float*)d_in[9];
  const float* conv_w  = (const float*)d_in[10];
  const float* dt_w    = (const float*)d_in[11];
  const float* dt_b    = (const float*)d_in[12];
  const float* D_p     = (const float*)d_in[13];
  const float* out_w   = (const float*)d_in[14];
  const float* ln2_g   = (const float*)d_in[15];
  const float* ln2_b   = (const float*)d_in[16];
  const float* mlp_w1  = (const float*)d_in[17];
  const float* mlp_b1  = (const float*)d_in[18];
  const float* mlp_w2  = (const float*)d_in[19];
  const float* mlp_b2  = (const float*)d_in[20];
  const float* lno_g   = (const float*)d_in[21];
  const float* lno_b   = (const float*)d_in[22];
  const float* head_w  = (const float*)d_in[23];
  const float* head_b  = (const float*)d_in[24];

  char* w = (char*)d_ws;
  float* te    = (float*)w;  w += 4096;
  float* x     = (float*)w;  w += (size_t)M_TOK * DD * 4;      // residual, f32
  bf16*  aIn   = (bf16*)w;   w += (size_t)M_TOK * DD * 2;      // bf16 GEMM A inputs
  float* proj  = (float*)w;  w += (size_t)M_TOK * PW * 4;      // in-proj out (f32); aliased by mlp hidden
  float* ubuf  = (float*)w;  w += (size_t)M_TOK * DD * 4;
  float* dtbuf = (float*)w;  w += (size_t)M_TOK * DD * 4;
  float* ybuf  = (float*)w;  w += (size_t)M_TOK * DD * 4;      // yloc
  float* Ebuf  = (float*)w;  w += (size_t)M_TOK * DD * 4;
  float* Aprod = (float*)w;  w += (size_t)2 * NCH * NST * DD * 4;
  float* hend  = (float*)w;  w += (size_t)2 * NCH * NST * DD * 4;
  float* h0    = (float*)w;  w += (size_t)2 * NCH * NST * DD * 4;
  bf16*  gbuf  = (bf16*)proj;                                  // mlp hidden bf16 [M,2048]

  k_time_embed<<<2, 256, 0, stream>>>(t, tmlp_w1, tmlp_b1, tmlp_w2, tmlp_b2, te);
  k_embed<<<M_TOK, 256, 0, stream>>>(x_t, tok_emb, te, x);

  for (int i = 0; i < 6; ++i) {
    const float* inw_i  = in_w   + (size_t)i * PW * DD;
    const float* cw_i   = conv_w + (size_t)i * DD * 4;
    const float* dtw_i  = dt_w   + (size_t)i * DD * RR;
    const float* dtb_i  = dt_b   + (size_t)i * DD;
    const float* dp_i   = D_p    + (size_t)i * DD;
    const float* ow_i   = out_w  + (size_t)i * DD * DD;
    const float* m1_i   = mlp_w1 + (size_t)i * DFFW * DD;
    const float* m1b_i  = mlp_b1 + (size_t)i * DFFW;
    const float* m2_i   = mlp_w2 + (size_t)i * DD * DFFW;
    const float* m2b_i  = mlp_b2 + (size_t)i * DD;

    k_layernorm<<<M_TOK, 256, 0, stream>>>(x, ln1_g + i * DD, ln1_b + i * DD, aIn);
    gemm_abt<0,false,false,false,false><<<dim3((PW + 127) / 128, M_TOK / 128), 256, 0, stream>>>(
        aIn, inw_i, nullptr, nullptr, proj, PW, DD);
    k_conv_dt<<<M_TOK * 2, 256, 0, stream>>>(proj, cw_i, dtw_i, dtb_i, ubuf, dtbuf);
    k_scan1<<<dim3(4, NCH, 2), 128, 0, stream>>>(proj, ubuf, dtbuf, ybuf, Ebuf, Aprod, hend);
    k_scan2<<<2 * NST * DD / 256, 256, 0, stream>>>(Aprod, hend, h0);
    k_scan3<<<dim3(4, NCH, 2), 128, 0, stream>>>(proj, ubuf, ybuf, Ebuf, h0, dp_i, aIn);
    gemm64<0,false,true,false><<<dim3(DD / 64, M_TOK / 64), 256, 0, stream>>>(
        aIn, ow_i, nullptr, x, x, DD, DD);
    k_layernorm<<<M_TOK, 256, 0, stream>>>(x, ln2_g + i * DD, ln2_b + i * DD, aIn);
    gemm_abt<1,true,false,true,false><<<dim3(DFFW / 128, M_TOK / 128), 256, 0, stream>>>(
        aIn, m1_i, m1b_i, nullptr, gbuf, DFFW, DD);
    gemm64<0,false,true,true><<<dim3(DD / 64, M_TOK / 64), 256, 0, stream>>>(
        gbuf, m2_i, m2b_i, x, x, DD, DFFW);
  }

  k_layernorm<<<M_TOK, 256, 0, stream>>>(x, lno_g, lno_b, aIn);
  // head: grid.x = M-tiles so consecutive blocks share the same B panel (L2/L3 reuse)
  gemm_abt<0,false,false,true,true><<<dim3(M_TOK / 128, (50000 + 127) / 128), 256, 0, stream>>>(
      aIn, head_w, head_b, nullptr, d_out, 50000, DD);
}

// Round 5
// 1271.685 us; speedup vs baseline: 3.7367x; 1.2600x over previous
//
#include <hip/hip_runtime.h>
#include <hip/hip_bf16.h>
#include <math.h>

typedef __hip_bfloat16 bf16;
typedef short s16x8 __attribute__((ext_vector_type(8)));
typedef float f32x4 __attribute__((ext_vector_type(4)));

#define M_TOK 2048
#define DD    512
#define LSEQ  1024
#define PW    1088   /* 2D + R + 2N */
#define NST   16
#define RR    32
#define DFFW  2048
#define NCH   64     /* chunks per sequence */
#define CH    16     /* chunk length (NCH*CH == LSEQ) */

__device__ __forceinline__ float bf2f(bf16 v) { return __bfloat162float(v); }
__device__ __forceinline__ float siluf(float x) { return x / (1.f + expf(-x)); }

__constant__ float c_invn[NST] = {
  -1.f/1, -1.f/2, -1.f/3, -1.f/4, -1.f/5, -1.f/6, -1.f/7, -1.f/8,
  -1.f/9, -1.f/10, -1.f/11, -1.f/12, -1.f/13, -1.f/14, -1.f/15, -1.f/16 };

// ---------------- time embedding MLP, pass 1: h1 = silu(emb @ w1^T + b1) ----------------
// one wave per hidden unit j, both batch elements per wave. grid(512), 256 thr.
__global__ __launch_bounds__(256) void k_te1(
    const int* __restrict__ t, const float* __restrict__ w1, const float* __restrict__ b1,
    float* __restrict__ h1)
{
  __shared__ float semb[2][512];
  int tid = threadIdx.x;
  float t0 = (float)t[0], t1 = (float)t[1];
  {
    int k = tid;                      // 0..255
    float f = expf((float)k * (-9.210340371976184f / 255.f));
    semb[0][k]       = sinf(t0 * f);
    semb[0][k + 256] = cosf(t0 * f);
    semb[1][k]       = sinf(t1 * f);
    semb[1][k + 256] = cosf(t1 * f);
  }
  __syncthreads();
  int wave = tid >> 6, lane = tid & 63;
  int j = blockIdx.x * 4 + wave;      // 0..2047
  const float* wr = w1 + (size_t)j * 512;
  float s0 = 0.f, s1 = 0.f;
#pragma unroll
  for (int i = 0; i < 8; ++i) {
    int k = lane + (i << 6);
    float wv = wr[k];
    s0 += wv * semb[0][k];
    s1 += wv * semb[1][k];
  }
  for (int o = 32; o; o >>= 1) { s0 += __shfl_down(s0, o); s1 += __shfl_down(s1, o); }
  if (!lane) {
    float bv = b1[j];
    h1[j]        = siluf(s0 + bv);
    h1[2048 + j] = siluf(s1 + bv);
  }
}

// ---------------- time embedding MLP, pass 2: te = h1 @ w2^T + b2 ----------------
// one wave per output d. grid(128), 256 thr.
__global__ __launch_bounds__(256) void k_te2(
    const float* __restrict__ h1, const float* __restrict__ w2, const float* __restrict__ b2,
    float* __restrict__ te)
{
  __shared__ float sh1[2][2048];
  int tid = threadIdx.x;
  for (int idx = tid; idx < 4096; idx += 256)
    sh1[idx >> 11][idx & 2047] = h1[idx];
  __syncthreads();
  int wave = tid >> 6, lane = tid & 63;
  int d = blockIdx.x * 4 + wave;      // 0..511
  const float* wr = w2 + (size_t)d * 2048;
  float s0 = 0.f, s1 = 0.f;
#pragma unroll
  for (int i = 0; i < 32; ++i) {
    int k = lane + (i << 6);
    float wv = wr[k];
    s0 += wv * sh1[0][k];
    s1 += wv * sh1[1][k];
  }
  for (int o = 32; o; o >>= 1) { s0 += __shfl_down(s0, o); s1 += __shfl_down(s1, o); }
  if (!lane) {
    float bv = b2[d];
    te[d]       = s0 + bv;
    te[512 + d] = s1 + bv;
  }
}

// ---------------- token embed + time embed add ----------------
__global__ __launch_bounds__(256) void k_embed(
    const int* __restrict__ x_t, const float* __restrict__ tok,
    const float* __restrict__ te, float* __restrict__ x)
{
  int m = blockIdx.x;              // 0..2047
  int b = m >> 10;
  int row = x_t[m];
  const float* src = tok + (size_t)row * DD;
  for (int d = threadIdx.x; d < DD; d += 256)
    x[(size_t)m * DD + d] = src[d] + te[b * DD + d];
}

// ---------------- LayerNorm (row of 512) -> bf16 ----------------
__global__ __launch_bounds__(256) void k_layernorm(
    const float* __restrict__ x, const float* __restrict__ g, const float* __restrict__ bb,
    bf16* __restrict__ out)
{
  int m = blockIdx.x;
  const float* xr = x + (size_t)m * DD;
  float2 v = ((const float2*)xr)[threadIdx.x];
  float s = v.x + v.y, ss = v.x * v.x + v.y * v.y;
  for (int o = 32; o; o >>= 1) { s += __shfl_down(s, o); ss += __shfl_down(ss, o); }
  __shared__ float ps[4], pss[4];
  int wave = threadIdx.x >> 6, lane = threadIdx.x & 63;
  if (!lane) { ps[wave] = s; pss[wave] = ss; }
  __syncthreads();
  s = ps[0] + ps[1] + ps[2] + ps[3];
  ss = pss[0] + pss[1] + pss[2] + pss[3];
  float mu = s * (1.f / DD);
  float var = ss * (1.f / DD) - mu * mu;
  float inv = rsqrtf(var + 1e-5f);
  int d = threadIdx.x * 2;
  out[(size_t)m * DD + d]     = __float2bfloat16((v.x - mu) * inv * g[d]     + bb[d]);
  out[(size_t)m * DD + d + 1] = __float2bfloat16((v.y - mu) * inv * g[d + 1] + bb[d + 1]);
}

// ---------------- depthwise causal conv + silu, and dt = softplus(dtu@Wdt^T+b) ----------------
__global__ __launch_bounds__(256) void k_conv_dt(
    const float* __restrict__ proj, const float* __restrict__ convw,
    const float* __restrict__ dtw, const float* __restrict__ dtb,
    float* __restrict__ u, float* __restrict__ dt)
{
  int m = blockIdx.x >> 1;
  int d = ((blockIdx.x & 1) << 8) + threadIdx.x;
  int b = m >> 10, l = m & 1023;
  __shared__ float dtu[RR];
  if (threadIdx.x < RR) dtu[threadIdx.x] = proj[(size_t)m * PW + 2 * DD + threadIdx.x];
  __syncthreads();
  float c = 0.f;
#pragma unroll
  for (int j = 0; j < 4; ++j) {
    int ll = l - 3 + j;
    if (ll >= 0) c += proj[(size_t)(b * LSEQ + ll) * PW + d] * convw[d * 4 + j];
  }
  u[(size_t)m * DD + d] = siluf(c);
  float s = dtb[d];
  const float* wr = dtw + (size_t)d * RR;
#pragma unroll
  for (int r = 0; r < RR; ++r) s += dtu[r] * wr[r];
  dt[(size_t)m * DD + d] = (s > 0.f) ? (s + log1pf(expf(-s))) : log1pf(expf(s));
}

// ---------------- scan pass 1: local chunk scans ----------------
__global__ __launch_bounds__(128) void k_scan1(
    const float* __restrict__ proj, const float* __restrict__ u,
    const float* __restrict__ dt, float* __restrict__ yloc,
    float* __restrict__ Ebuf, float* __restrict__ Aprod, float* __restrict__ hend)
{
  int d = (blockIdx.x << 7) + threadIdx.x;
  int c = blockIdx.y, b = blockIdx.z;
  int m0 = b * LSEQ + c * CH;
  __shared__ float sBC[CH][32];   // [l][0..15]=B, [16..31]=C
  for (int idx = threadIdx.x; idx < CH * 32; idx += 128)
    sBC[idx >> 5][idx & 31] = proj[(size_t)(m0 + (idx >> 5)) * PW + 2 * DD + RR + (idx & 31)];
  __syncthreads();
  float h[NST];
#pragma unroll
  for (int n = 0; n < NST; ++n) h[n] = 0.f;
  float S = 0.f;
  for (int l = 0; l < CH; ++l) {
    size_t m = (size_t)(m0 + l);
    float dtv = dt[m * DD + d];
    float uv  = u[m * DD + d];
    float e1 = expf(-dtv);
    S += dtv;
    Ebuf[m * DD + d] = expf(-S);
    float p = 1.f, acc = 0.f;
#pragma unroll
    for (int n = 0; n < NST; ++n) {
      p *= e1;                                    // e1^(n+1)
      float bu = (p - 1.f) * c_invn[n] * sBC[l][n] * uv;
      h[n] = p * h[n] + bu;
      acc += sBC[l][16 + n] * h[n];
    }
    yloc[m * DD + d] = acc;
  }
  float Ec = expf(-S);
  float p = 1.f;
  size_t base = ((size_t)(b * NCH + c) * NST) * DD + d;
#pragma unroll
  for (int n = 0; n < NST; ++n) {
    p *= Ec;
    Aprod[base + (size_t)n * DD] = p;
    hend [base + (size_t)n * DD] = h[n];
  }
}

// ---------------- scan pass 2: prefix combine over chunks ----------------
__global__ __launch_bounds__(256) void k_scan2(
    const float* __restrict__ Aprod, const float* __restrict__ hend, float* __restrict__ h0)
{
  int idx = blockIdx.x * 256 + threadIdx.x;   // [b][n][d]
  int d = idx & 511;
  int n = (idx >> 9) & 15;
  int b = idx >> 13;
  float h = 0.f;
  for (int c = 0; c < NCH; ++c) {
    size_t o = ((size_t)((b * NCH + c) * NST + n)) * DD + d;
    h0[o] = h;
    h = Aprod[o] * h + hend[o];
  }
}

// ---------------- scan pass 3 + gate ----------------
__global__ __launch_bounds__(128) void k_scan3(
    const float* __restrict__ proj, const float* __restrict__ u,
    const float* __restrict__ yloc, const float* __restrict__ Ebuf,
    const float* __restrict__ h0, const float* __restrict__ Dp, bf16* __restrict__ out)
{
  int d = (blockIdx.x << 7) + threadIdx.x;
  int c = blockIdx.y, b = blockIdx.z;
  int m0 = b * LSEQ + c * CH;
  __shared__ float sC[CH][NST];
  for (int idx = threadIdx.x; idx < CH * NST; idx += 128)
    sC[idx >> 4][idx & 15] = proj[(size_t)(m0 + (idx >> 4)) * PW + 2 * DD + RR + NST + (idx & 15)];
  __syncthreads();
  float hh[NST];
  size_t base = ((size_t)(b * NCH + c) * NST) * DD + d;
#pragma unroll
  for (int n = 0; n < NST; ++n) hh[n] = h0[base + (size_t)n * DD];
  float dpv = Dp[d];
  for (int l = 0; l < CH; ++l) {
    size_t m = (size_t)(m0 + l);
    float E = Ebuf[m * DD + d];
    float p = 1.f, corr = 0.f;
#pragma unroll
    for (int n = 0; n < NST; ++n) {
      p *= E;                                     // E^(n+1)
      corr += sC[l][n] * p * hh[n];
    }
    float y = yloc[m * DD + d] + corr;
    float z = proj[m * PW + DD + d];
    float v = (y + u[m * DD + d] * dpv) * siluf(z);
    out[m * DD + d] = __float2bfloat16(v);
  }
}

// ---------------- 128x128 MFMA GEMM with 2-phase prefetch ----------------
// C[m,n] = sum_k A[m,k]*B[n,k]. A bf16 [M,K]; B f32 [N,K] (cvt to bf16 in staging).
// TRANS: grid.x = M-tiles (consecutive blocks share B panel -> L2 reuse).
template<int ACT, bool BF16OUT, bool RES, bool BIAS, bool TRANS>
__global__ __launch_bounds__(256) void gemm_abt(
    const bf16* __restrict__ A, const float* __restrict__ B,
    const float* __restrict__ bias, const float* __restrict__ res,
    void* __restrict__ Cout, int N, int K)
{
  __shared__ bf16 sA[128][40];   // +8 pad: row stride 80B = 20 banks -> conflict-free
  __shared__ bf16 sB[128][40];
  int bn = (TRANS ? blockIdx.y : blockIdx.x) * 128;
  int bm = (TRANS ? blockIdx.x : blockIdx.y) * 128;
  int tid = threadIdx.x;
  int wave = tid >> 6, lane = tid & 63;
  int wm = (wave >> 1) << 6, wn = (wave & 1) << 6;
  int r = lane & 15, q = lane >> 4;
  int ldr = tid >> 2;
  int ldc = (tid & 3) << 3;

  f32x4 acc[4][4];
#pragma unroll
  for (int i = 0; i < 4; ++i)
#pragma unroll
    for (int j = 0; j < 4; ++j) acc[i][j] = (f32x4){0.f, 0.f, 0.f, 0.f};

  s16x8 pa[2];
  f32x4 pb[2][2];
#define GLOAD(k0)                                                              \
  {                                                                            \
    _Pragma("unroll")                                                          \
    for (int h = 0; h < 2; ++h) {                                              \
      int row = ldr + (h << 6);                                                \
      pa[h] = *(const s16x8*)(A + (size_t)(bm + row) * K + (k0) + ldc);        \
      int nrow = bn + row;                                                     \
      if (nrow < N) {                                                          \
        const float* src = B + (size_t)nrow * K + (k0) + ldc;                  \
        pb[h][0] = *(const f32x4*)src;                                         \
        pb[h][1] = *(const f32x4*)(src + 4);                                   \
      } else {                                                                 \
        pb[h][0] = (f32x4){0.f,0.f,0.f,0.f};                                   \
        pb[h][1] = (f32x4){0.f,0.f,0.f,0.f};                                   \
      }                                                                        \
    }                                                                          \
  }

  GLOAD(0);
  for (int k0 = 0; k0 < K; k0 += 32) {
#pragma unroll
    for (int h = 0; h < 2; ++h) {
      int row = ldr + (h << 6);
      *(s16x8*)&sA[row][ldc] = pa[h];
      bf16* dst = &sB[row][ldc];
      dst[0] = __float2bfloat16(pb[h][0][0]); dst[1] = __float2bfloat16(pb[h][0][1]);
      dst[2] = __float2bfloat16(pb[h][0][2]); dst[3] = __float2bfloat16(pb[h][0][3]);
      dst[4] = __float2bfloat16(pb[h][1][0]); dst[5] = __float2bfloat16(pb[h][1][1]);
      dst[6] = __float2bfloat16(pb[h][1][2]); dst[7] = __float2bfloat16(pb[h][1][3]);
    }
    __syncthreads();
    if (k0 + 32 < K) GLOAD(k0 + 32);   // overlap next tile's HBM latency with MFMA
    s16x8 af[4], bg[4];
#pragma unroll
    for (int i = 0; i < 4; ++i) af[i] = *(s16x8*)&sA[wm + i * 16 + r][q << 3];
#pragma unroll
    for (int j = 0; j < 4; ++j) bg[j] = *(s16x8*)&sB[wn + j * 16 + r][q << 3];
#pragma unroll
    for (int i = 0; i < 4; ++i)
#pragma unroll
      for (int j = 0; j < 4; ++j)
        acc[i][j] = __builtin_amdgcn_mfma_f32_16x16x32_bf16(af[i], bg[j], acc[i][j], 0, 0, 0);
    __syncthreads();
  }
#undef GLOAD

#pragma unroll
  for (int i = 0; i < 4; ++i)
#pragma unroll
    for (int j = 0; j < 4; ++j) {
      int n = bn + wn + j * 16 + r;
      if (n >= N) continue;
#pragma unroll
      for (int e = 0; e < 4; ++e) {
        int m = bm + wm + i * 16 + (q << 2) + e;
        float v = acc[i][j][e];
        if (BIAS) v += bias[n];
        if (ACT == 1) v = 0.5f * v * (1.f + erff(v * 0.70710678118f));  // exact GELU
        if (RES) v += res[(size_t)m * N + n];
        if (BF16OUT) ((bf16*)Cout)[(size_t)m * N + n] = __float2bfloat16(v);
        else         ((float*)Cout)[(size_t)m * N + n] = v;
      }
    }
}

// ---------------- 64x64 MFMA GEMM (more blocks for small N) ----------------
// Requires M%64==0, N%64==0, K%32==0. grid (N/64, M/64).
template<int ACT, bool BF16OUT, bool RES, bool BIAS>
__global__ __launch_bounds__(256) void gemm64(
    const bf16* __restrict__ A, const float* __restrict__ B,
    const float* __restrict__ bias, const float* __restrict__ res,
    void* __restrict__ Cout, int N, int K)
{
  __shared__ bf16 sA[64][40];
  __shared__ bf16 sB[64][40];
  int bn = blockIdx.x * 64;
  int bm = blockIdx.y * 64;
  int tid = threadIdx.x;
  int wave = tid >> 6, lane = tid & 63;
  int wm = (wave >> 1) << 5, wn = (wave & 1) << 5;
  int r = lane & 15, q = lane >> 4;
  int ldr = tid >> 2;
  int ldc = (tid & 3) << 3;

  f32x4 acc[2][2];
#pragma unroll
  for (int i = 0; i < 2; ++i)
#pragma unroll
    for (int j = 0; j < 2; ++j) acc[i][j] = (f32x4){0.f, 0.f, 0.f, 0.f};

  s16x8 pa;
  f32x4 pb[2];
#define GLOAD64(k0)                                                            \
  {                                                                            \
    pa = *(const s16x8*)(A + (size_t)(bm + ldr) * K + (k0) + ldc);             \
    const float* src = B + (size_t)(bn + ldr) * K + (k0) + ldc;                \
    pb[0] = *(const f32x4*)src;                                                \
    pb[1] = *(const f32x4*)(src + 4);                                          \
  }

  GLOAD64(0);
  for (int k0 = 0; k0 < K; k0 += 32) {
    *(s16x8*)&sA[ldr][ldc] = pa;
    {
      bf16* dst = &sB[ldr][ldc];
      dst[0] = __float2bfloat16(pb[0][0]); dst[1] = __float2bfloat16(pb[0][1]);
      dst[2] = __float2bfloat16(pb[0][2]); dst[3] = __float2bfloat16(pb[0][3]);
      dst[4] = __float2bfloat16(pb[1][0]); dst[5] = __float2bfloat16(pb[1][1]);
      dst[6] = __float2bfloat16(pb[1][2]); dst[7] = __float2bfloat16(pb[1][3]);
    }
    __syncthreads();
    if (k0 + 32 < K) GLOAD64(k0 + 32);
    s16x8 af[2], bg[2];
#pragma unroll
    for (int i = 0; i < 2; ++i) af[i] = *(s16x8*)&sA[wm + i * 16 + r][q << 3];
#pragma unroll
    for (int j = 0; j < 2; ++j) bg[j] = *(s16x8*)&sB[wn + j * 16 + r][q << 3];
#pragma unroll
    for (int i = 0; i < 2; ++i)
#pragma unroll
      for (int j = 0; j < 2; ++j)
        acc[i][j] = __builtin_amdgcn_mfma_f32_16x16x32_bf16(af[i], bg[j], acc[i][j], 0, 0, 0);
    __syncthreads();
  }
#undef GLOAD64

#pragma unroll
  for (int i = 0; i < 2; ++i)
#pragma unroll
    for (int j = 0; j < 2; ++j) {
      int n = bn + wn + j * 16 + r;
#pragma unroll
      for (int e = 0; e < 4; ++e) {
        int m = bm + wm + i * 16 + (q << 2) + e;
        float v = acc[i][j][e];
        if (BIAS) v += bias[n];
        if (ACT == 1) v = 0.5f * v * (1.f + erff(v * 0.70710678118f));
        if (RES) v += res[(size_t)m * N + n];
        if (BF16OUT) ((bf16*)Cout)[(size_t)m * N + n] = __float2bfloat16(v);
        else         ((float*)Cout)[(size_t)m * N + n] = v;
      }
    }
}

// ---------------- launch ----------------
extern "C" void kernel_launch(void* const* d_in, const int* in_sizes, int n_in,
                              void* d_out, int out_size, void* d_ws, size_t ws_size,
                              hipStream_t stream) {
  const int*   x_t     = (const int*)d_in[0];
  const int*   t       = (const int*)d_in[1];
  const float* tok_emb = (const float*)d_in[2];
  const float* tmlp_w1 = (const float*)d_in[3];
  const float* tmlp_b1 = (const float*)d_in[4];
  const float* tmlp_w2 = (const float*)d_in[5];
  const float* tmlp_b2 = (const float*)d_in[6];
  const float* ln1_g   = (const float*)d_in[7];
  const float* ln1_b   = (const float*)d_in[8];
  const float* in_w    = (const float*)d_in[9];
  const float* conv_w  = (const float*)d_in[10];
  const float* dt_w    = (const float*)d_in[11];
  const float* dt_b    = (const float*)d_in[12];
  const float* D_p     = (const float*)d_in[13];
  const float* out_w   = (const float*)d_in[14];
  const float* ln2_g   = (const float*)d_in[15];
  const float* ln2_b   = (const float*)d_in[16];
  const float* mlp_w1  = (const float*)d_in[17];
  const float* mlp_b1  = (const float*)d_in[18];
  const float* mlp_w2  = (const float*)d_in[19];
  const float* mlp_b2  = (const float*)d_in[20];
  const float* lno_g   = (const float*)d_in[21];
  const float* lno_b   = (const float*)d_in[22];
  const float* head_w  = (const float*)d_in[23];
  const float* head_b  = (const float*)d_in[24];

  char* w = (char*)d_ws;
  float* te    = (float*)w;  w += 4096;
  float* h1t   = (float*)w;  w += 16384;                       // time-MLP hidden [2][2048]
  float* x     = (float*)w;  w += (size_t)M_TOK * DD * 4;      // residual, f32
  bf16*  aIn   = (bf16*)w;   w += (size_t)M_TOK * DD * 2;      // bf16 GEMM A inputs
  float* proj  = (float*)w;  w += (size_t)M_TOK * PW * 4;      // in-proj out (f32); aliased by mlp hidden
  float* ubuf  = (float*)w;  w += (size_t)M_TOK * DD * 4;
  float* dtbuf = (float*)w;  w += (size_t)M_TOK * DD * 4;
  float* ybuf  = (float*)w;  w += (size_t)M_TOK * DD * 4;      // yloc
  float* Ebuf  = (float*)w;  w += (size_t)M_TOK * DD * 4;
  float* Aprod = (float*)w;  w += (size_t)2 * NCH * NST * DD * 4;
  float* hend  = (float*)w;  w += (size_t)2 * NCH * NST * DD * 4;
  float* h0    = (float*)w;  w += (size_t)2 * NCH * NST * DD * 4;
  bf16*  gbuf  = (bf16*)proj;                                  // mlp hidden bf16 [M,2048]

  k_te1<<<512, 256, 0, stream>>>(t, tmlp_w1, tmlp_b1, h1t);
  k_te2<<<128, 256, 0, stream>>>(h1t, tmlp_w2, tmlp_b2, te);
  k_embed<<<M_TOK, 256, 0, stream>>>(x_t, tok_emb, te, x);

  for (int i = 0; i < 6; ++i) {
    const float* inw_i  = in_w   + (size_t)i * PW * DD;
    const float* cw_i   = conv_w + (size_t)i * DD * 4;
    const float* dtw_i  = dt_w   + (size_t)i * DD * RR;
    const float* dtb_i  = dt_b   + (size_t)i * DD;
    const float* dp_i   = D_p    + (size_t)i * DD;
    const float* ow_i   = out_w  + (size_t)i * DD * DD;
    const float* m1_i   = mlp_w1 + (size_t)i * DFFW * DD;
    const float* m1b_i  = mlp_b1 + (size_t)i * DFFW;
    const float* m2_i   = mlp_w2 + (size_t)i * DD * DFFW;
    const float* m2b_i  = mlp_b2 + (size_t)i * DD;

    k_layernorm<<<M_TOK, 256, 0, stream>>>(x, ln1_g + i * DD, ln1_b + i * DD, aIn);
    gemm64<0,false,false,false><<<dim3(PW / 64, M_TOK / 64), 256, 0, stream>>>(
        aIn, inw_i, nullptr, nullptr, proj, PW, DD);
    k_conv_dt<<<M_TOK * 2, 256, 0, stream>>>(proj, cw_i, dtw_i, dtb_i, ubuf, dtbuf);
    k_scan1<<<dim3(4, NCH, 2), 128, 0, stream>>>(proj, ubuf, dtbuf, ybuf, Ebuf, Aprod, hend);
    k_scan2<<<2 * NST * DD / 256, 256, 0, stream>>>(Aprod, hend, h0);
    k_scan3<<<dim3(4, NCH, 2), 128, 0, stream>>>(proj, ubuf, ybuf, Ebuf, h0, dp_i, aIn);
    gemm64<0,false,true,false><<<dim3(DD / 64, M_TOK / 64), 256, 0, stream>>>(
        aIn, ow_i, nullptr, x, x, DD, DD);
    k_layernorm<<<M_TOK, 256, 0, stream>>>(x, ln2_g + i * DD, ln2_b + i * DD, aIn);
    gemm_abt<1,true,false,true,false><<<dim3(DFFW / 128, M_TOK / 128), 256, 0, stream>>>(
        aIn, m1_i, m1b_i, nullptr, gbuf, DFFW, DD);
    gemm64<0,false,true,true><<<dim3(DD / 64, M_TOK / 64), 256, 0, stream>>>(
        gbuf, m2_i, m2b_i, x, x, DD, DFFW);
  }

  k_layernorm<<<M_TOK, 256, 0, stream>>>(x, lno_g, lno_b, aIn);
  // head: grid.x = M-tiles so consecutive blocks share the same B panel (L2/L3 reuse)
  gemm_abt<0,false,false,true,true><<<dim3(M_TOK / 128, (50000 + 127) / 128), 256, 0, stream>>>(
      aIn, head_w, head_b, nullptr, d_out, 50000, DD);
}

// Round 6
// 1222.237 us; speedup vs baseline: 3.8879x; 1.0405x over previous
//
#include <hip/hip_runtime.h>
#include <hip/hip_bf16.h>
#include <math.h>

typedef __hip_bfloat16 bf16;
typedef short s16x8 __attribute__((ext_vector_type(8)));
typedef float f32x4 __attribute__((ext_vector_type(4)));

#define M_TOK 2048
#define DD    512
#define LSEQ  1024
#define PW    1088   /* 2D + R + 2N */
#define NST   16
#define RR    32
#define DFFW  2048
#define NCH   64     /* chunks per sequence */
#define CH    16     /* chunk length (NCH*CH == LSEQ) */
#define PAD   36     /* LDS row stride in elems: 72B = 18 banks -> uniform 2-way (free) */

__device__ __forceinline__ float bf2f(bf16 v) { return __bfloat162float(v); }
__device__ __forceinline__ float siluf(float x) { return x / (1.f + expf(-x)); }

// pack 8 f32 -> 8 bf16 in one 16B register (single ds_write_b128 at the store site)
__device__ __forceinline__ s16x8 cvt8(const f32x4& a, const f32x4& b) {
  s16x8 r;
  r[0] = (short)__bfloat16_as_ushort(__float2bfloat16(a[0]));
  r[1] = (short)__bfloat16_as_ushort(__float2bfloat16(a[1]));
  r[2] = (short)__bfloat16_as_ushort(__float2bfloat16(a[2]));
  r[3] = (short)__bfloat16_as_ushort(__float2bfloat16(a[3]));
  r[4] = (short)__bfloat16_as_ushort(__float2bfloat16(b[0]));
  r[5] = (short)__bfloat16_as_ushort(__float2bfloat16(b[1]));
  r[6] = (short)__bfloat16_as_ushort(__float2bfloat16(b[2]));
  r[7] = (short)__bfloat16_as_ushort(__float2bfloat16(b[3]));
  return r;
}

__constant__ float c_invn[NST] = {
  -1.f/1, -1.f/2, -1.f/3, -1.f/4, -1.f/5, -1.f/6, -1.f/7, -1.f/8,
  -1.f/9, -1.f/10, -1.f/11, -1.f/12, -1.f/13, -1.f/14, -1.f/15, -1.f/16 };

// ---------------- time embedding MLP, pass 1 ----------------
__global__ __launch_bounds__(256) void k_te1(
    const int* __restrict__ t, const float* __restrict__ w1, const float* __restrict__ b1,
    float* __restrict__ h1)
{
  __shared__ float semb[2][512];
  int tid = threadIdx.x;
  float t0 = (float)t[0], t1 = (float)t[1];
  {
    int k = tid;
    float f = expf((float)k * (-9.210340371976184f / 255.f));
    semb[0][k]       = sinf(t0 * f);
    semb[0][k + 256] = cosf(t0 * f);
    semb[1][k]       = sinf(t1 * f);
    semb[1][k + 256] = cosf(t1 * f);
  }
  __syncthreads();
  int wave = tid >> 6, lane = tid & 63;
  int j = blockIdx.x * 4 + wave;
  const float* wr = w1 + (size_t)j * 512;
  float s0 = 0.f, s1 = 0.f;
#pragma unroll
  for (int i = 0; i < 8; ++i) {
    int k = lane + (i << 6);
    float wv = wr[k];
    s0 += wv * semb[0][k];
    s1 += wv * semb[1][k];
  }
  for (int o = 32; o; o >>= 1) { s0 += __shfl_down(s0, o); s1 += __shfl_down(s1, o); }
  if (!lane) {
    float bv = b1[j];
    h1[j]        = siluf(s0 + bv);
    h1[2048 + j] = siluf(s1 + bv);
  }
}

// ---------------- time embedding MLP, pass 2 ----------------
__global__ __launch_bounds__(256) void k_te2(
    const float* __restrict__ h1, const float* __restrict__ w2, const float* __restrict__ b2,
    float* __restrict__ te)
{
  __shared__ float sh1[2][2048];
  int tid = threadIdx.x;
  for (int idx = tid; idx < 4096; idx += 256)
    sh1[idx >> 11][idx & 2047] = h1[idx];
  __syncthreads();
  int wave = tid >> 6, lane = tid & 63;
  int d = blockIdx.x * 4 + wave;
  const float* wr = w2 + (size_t)d * 2048;
  float s0 = 0.f, s1 = 0.f;
#pragma unroll
  for (int i = 0; i < 32; ++i) {
    int k = lane + (i << 6);
    float wv = wr[k];
    s0 += wv * sh1[0][k];
    s1 += wv * sh1[1][k];
  }
  for (int o = 32; o; o >>= 1) { s0 += __shfl_down(s0, o); s1 += __shfl_down(s1, o); }
  if (!lane) {
    float bv = b2[d];
    te[d]       = s0 + bv;
    te[512 + d] = s1 + bv;
  }
}

// ---------------- token embed + time embed add ----------------
__global__ __launch_bounds__(256) void k_embed(
    const int* __restrict__ x_t, const float* __restrict__ tok,
    const float* __restrict__ te, float* __restrict__ x)
{
  int m = blockIdx.x;
  int b = m >> 10;
  int row = x_t[m];
  const float* src = tok + (size_t)row * DD;
  for (int d = threadIdx.x; d < DD; d += 256)
    x[(size_t)m * DD + d] = src[d] + te[b * DD + d];
}

// ---------------- LayerNorm (row of 512) -> bf16 ----------------
__global__ __launch_bounds__(256) void k_layernorm(
    const float* __restrict__ x, const float* __restrict__ g, const float* __restrict__ bb,
    bf16* __restrict__ out)
{
  int m = blockIdx.x;
  const float* xr = x + (size_t)m * DD;
  float2 v = ((const float2*)xr)[threadIdx.x];
  float s = v.x + v.y, ss = v.x * v.x + v.y * v.y;
  for (int o = 32; o; o >>= 1) { s += __shfl_down(s, o); ss += __shfl_down(ss, o); }
  __shared__ float ps[4], pss[4];
  int wave = threadIdx.x >> 6, lane = threadIdx.x & 63;
  if (!lane) { ps[wave] = s; pss[wave] = ss; }
  __syncthreads();
  s = ps[0] + ps[1] + ps[2] + ps[3];
  ss = pss[0] + pss[1] + pss[2] + pss[3];
  float mu = s * (1.f / DD);
  float var = ss * (1.f / DD) - mu * mu;
  float inv = rsqrtf(var + 1e-5f);
  int d = threadIdx.x * 2;
  out[(size_t)m * DD + d]     = __float2bfloat16((v.x - mu) * inv * g[d]     + bb[d]);
  out[(size_t)m * DD + d + 1] = __float2bfloat16((v.y - mu) * inv * g[d + 1] + bb[d + 1]);
}

// ---------------- depthwise causal conv + silu, dt = softplus ----------------
__global__ __launch_bounds__(256) void k_conv_dt(
    const float* __restrict__ proj, const float* __restrict__ convw,
    const float* __restrict__ dtw, const float* __restrict__ dtb,
    float* __restrict__ u, float* __restrict__ dt)
{
  int m = blockIdx.x >> 1;
  int d = ((blockIdx.x & 1) << 8) + threadIdx.x;
  int b = m >> 10, l = m & 1023;
  __shared__ float dtu[RR];
  if (threadIdx.x < RR) dtu[threadIdx.x] = proj[(size_t)m * PW + 2 * DD + threadIdx.x];
  __syncthreads();
  float c = 0.f;
#pragma unroll
  for (int j = 0; j < 4; ++j) {
    int ll = l - 3 + j;
    if (ll >= 0) c += proj[(size_t)(b * LSEQ + ll) * PW + d] * convw[d * 4 + j];
  }
  u[(size_t)m * DD + d] = siluf(c);
  float s = dtb[d];
  const float* wr = dtw + (size_t)d * RR;
#pragma unroll
  for (int r = 0; r < RR; ++r) s += dtu[r] * wr[r];
  dt[(size_t)m * DD + d] = (s > 0.f) ? (s + log1pf(expf(-s))) : log1pf(expf(s));
}

// ---------------- scan pass 1 ----------------
__global__ __launch_bounds__(128) void k_scan1(
    const float* __restrict__ proj, const float* __restrict__ u,
    const float* __restrict__ dt, float* __restrict__ yloc,
    float* __restrict__ Ebuf, float* __restrict__ Aprod, float* __restrict__ hend)
{
  int d = (blockIdx.x << 7) + threadIdx.x;
  int c = blockIdx.y, b = blockIdx.z;
  int m0 = b * LSEQ + c * CH;
  __shared__ float sBC[CH][32];
  for (int idx = threadIdx.x; idx < CH * 32; idx += 128)
    sBC[idx >> 5][idx & 31] = proj[(size_t)(m0 + (idx >> 5)) * PW + 2 * DD + RR + (idx & 31)];
  __syncthreads();
  float h[NST];
#pragma unroll
  for (int n = 0; n < NST; ++n) h[n] = 0.f;
  float S = 0.f;
  for (int l = 0; l < CH; ++l) {
    size_t m = (size_t)(m0 + l);
    float dtv = dt[m * DD + d];
    float uv  = u[m * DD + d];
    float e1 = expf(-dtv);
    S += dtv;
    Ebuf[m * DD + d] = expf(-S);
    float p = 1.f, acc = 0.f;
#pragma unroll
    for (int n = 0; n < NST; ++n) {
      p *= e1;
      float bu = (p - 1.f) * c_invn[n] * sBC[l][n] * uv;
      h[n] = p * h[n] + bu;
      acc += sBC[l][16 + n] * h[n];
    }
    yloc[m * DD + d] = acc;
  }
  float Ec = expf(-S);
  float p = 1.f;
  size_t base = ((size_t)(b * NCH + c) * NST) * DD + d;
#pragma unroll
  for (int n = 0; n < NST; ++n) {
    p *= Ec;
    Aprod[base + (size_t)n * DD] = p;
    hend [base + (size_t)n * DD] = h[n];
  }
}

// ---------------- scan pass 2 ----------------
__global__ __launch_bounds__(256) void k_scan2(
    const float* __restrict__ Aprod, const float* __restrict__ hend, float* __restrict__ h0)
{
  int idx = blockIdx.x * 256 + threadIdx.x;
  int d = idx & 511;
  int n = (idx >> 9) & 15;
  int b = idx >> 13;
  float h = 0.f;
  for (int c = 0; c < NCH; ++c) {
    size_t o = ((size_t)((b * NCH + c) * NST + n)) * DD + d;
    h0[o] = h;
    h = Aprod[o] * h + hend[o];
  }
}

// ---------------- scan pass 3 + gate ----------------
__global__ __launch_bounds__(128) void k_scan3(
    const float* __restrict__ proj, const float* __restrict__ u,
    const float* __restrict__ yloc, const float* __restrict__ Ebuf,
    const float* __restrict__ h0, const float* __restrict__ Dp, bf16* __restrict__ out)
{
  int d = (blockIdx.x << 7) + threadIdx.x;
  int c = blockIdx.y, b = blockIdx.z;
  int m0 = b * LSEQ + c * CH;
  __shared__ float sC[CH][NST];
  for (int idx = threadIdx.x; idx < CH * NST; idx += 128)
    sC[idx >> 4][idx & 15] = proj[(size_t)(m0 + (idx >> 4)) * PW + 2 * DD + RR + NST + (idx & 15)];
  __syncthreads();
  float hh[NST];
  size_t base = ((size_t)(b * NCH + c) * NST) * DD + d;
#pragma unroll
  for (int n = 0; n < NST; ++n) hh[n] = h0[base + (size_t)n * DD];
  float dpv = Dp[d];
  for (int l = 0; l < CH; ++l) {
    size_t m = (size_t)(m0 + l);
    float E = Ebuf[m * DD + d];
    float p = 1.f, corr = 0.f;
#pragma unroll
    for (int n = 0; n < NST; ++n) {
      p *= E;
      corr += sC[l][n] * p * hh[n];
    }
    float y = yloc[m * DD + d] + corr;
    float z = proj[m * PW + DD + d];
    float v = (y + u[m * DD + d] * dpv) * siluf(z);
    out[m * DD + d] = __float2bfloat16(v);
  }
}

// ---------------- 128x128 MFMA GEMM with 2-phase prefetch ----------------
// SWZ: bijective XCD chunk swizzle (requires gridDim.x*gridDim.y % 8 == 0) so
// consecutive same-XCD blocks walk M-tiles of one N-panel -> one L2 fetch per panel.
template<int ACT, bool BF16OUT, bool RES, bool BIAS, bool SWZ>
__global__ __launch_bounds__(256) void gemm_abt(
    const bf16* __restrict__ A, const float* __restrict__ B,
    const float* __restrict__ bias, const float* __restrict__ res,
    void* __restrict__ Cout, int N, int K)
{
  __shared__ bf16 sA[128][PAD];
  __shared__ bf16 sB[128][PAD];
  int bn, bm;
  if (SWZ) {
    int flat = blockIdx.y * gridDim.x + blockIdx.x;
    int q = (gridDim.x * gridDim.y) >> 3;
    int s = (flat & 7) * q + (flat >> 3);
    bm = (s % gridDim.x) * 128;     // gridDim.x = M-tiles
    bn = (s / gridDim.x) * 128;
  } else {
    bn = blockIdx.x * 128;
    bm = blockIdx.y * 128;
  }
  int tid = threadIdx.x;
  int wave = tid >> 6, lane = tid & 63;
  int wm = (wave >> 1) << 6, wn = (wave & 1) << 6;
  int r = lane & 15, q = lane >> 4;
  int ldr = tid >> 2;
  int ldc = (tid & 3) << 3;

  f32x4 acc[4][4];
#pragma unroll
  for (int i = 0; i < 4; ++i)
#pragma unroll
    for (int j = 0; j < 4; ++j) acc[i][j] = (f32x4){0.f, 0.f, 0.f, 0.f};

  s16x8 pa[2];
  f32x4 pb[2][2];
#define GLOAD(k0)                                                              \
  {                                                                            \
    _Pragma("unroll")                                                          \
    for (int h = 0; h < 2; ++h) {                                              \
      int row = ldr + (h << 6);                                                \
      pa[h] = *(const s16x8*)(A + (size_t)(bm + row) * K + (k0) + ldc);        \
      int nrow = bn + row;                                                     \
      if (nrow < N) {                                                          \
        const float* src = B + (size_t)nrow * K + (k0) + ldc;                  \
        pb[h][0] = *(const f32x4*)src;                                         \
        pb[h][1] = *(const f32x4*)(src + 4);                                   \
      } else {                                                                 \
        pb[h][0] = (f32x4){0.f,0.f,0.f,0.f};                                   \
        pb[h][1] = (f32x4){0.f,0.f,0.f,0.f};                                   \
      }                                                                        \
    }                                                                          \
  }

  GLOAD(0);
  for (int k0 = 0; k0 < K; k0 += 32) {
#pragma unroll
    for (int h = 0; h < 2; ++h) {
      int row = ldr + (h << 6);
      *(s16x8*)&sA[row][ldc] = pa[h];
      *(s16x8*)&sB[row][ldc] = cvt8(pb[h][0], pb[h][1]);   // one ds_write_b128
    }
    __syncthreads();
    if (k0 + 32 < K) GLOAD(k0 + 32);
    s16x8 af[4], bg[4];
#pragma unroll
    for (int i = 0; i < 4; ++i) af[i] = *(s16x8*)&sA[wm + i * 16 + r][q << 3];
#pragma unroll
    for (int j = 0; j < 4; ++j) bg[j] = *(s16x8*)&sB[wn + j * 16 + r][q << 3];
#pragma unroll
    for (int i = 0; i < 4; ++i)
#pragma unroll
      for (int j = 0; j < 4; ++j)
        acc[i][j] = __builtin_amdgcn_mfma_f32_16x16x32_bf16(af[i], bg[j], acc[i][j], 0, 0, 0);
    __syncthreads();
  }
#undef GLOAD

#pragma unroll
  for (int i = 0; i < 4; ++i)
#pragma unroll
    for (int j = 0; j < 4; ++j) {
      int n = bn + wn + j * 16 + r;
      if (n >= N) continue;
#pragma unroll
      for (int e = 0; e < 4; ++e) {
        int m = bm + wm + i * 16 + (q << 2) + e;
        float v = acc[i][j][e];
        if (BIAS) v += bias[n];
        if (ACT == 1) v = 0.5f * v * (1.f + erff(v * 0.70710678118f));
        if (RES) v += res[(size_t)m * N + n];
        if (BF16OUT) ((bf16*)Cout)[(size_t)m * N + n] = __float2bfloat16(v);
        else         ((float*)Cout)[(size_t)m * N + n] = v;
      }
    }
}

// ---------------- 64x64 MFMA GEMM ----------------
template<int ACT, bool BF16OUT, bool RES, bool BIAS>
__global__ __launch_bounds__(256) void gemm64(
    const bf16* __restrict__ A, const float* __restrict__ B,
    const float* __restrict__ bias, const float* __restrict__ res,
    void* __restrict__ Cout, int N, int K)
{
  __shared__ bf16 sA[64][PAD];
  __shared__ bf16 sB[64][PAD];
  int bn = blockIdx.x * 64;
  int bm = blockIdx.y * 64;
  int tid = threadIdx.x;
  int wave = tid >> 6, lane = tid & 63;
  int wm = (wave >> 1) << 5, wn = (wave & 1) << 5;
  int r = lane & 15, q = lane >> 4;
  int ldr = tid >> 2;
  int ldc = (tid & 3) << 3;

  f32x4 acc[2][2];
#pragma unroll
  for (int i = 0; i < 2; ++i)
#pragma unroll
    for (int j = 0; j < 2; ++j) acc[i][j] = (f32x4){0.f, 0.f, 0.f, 0.f};

  s16x8 pa;
  f32x4 pb[2];
#define GLOAD64(k0)                                                            \
  {                                                                            \
    pa = *(const s16x8*)(A + (size_t)(bm + ldr) * K + (k0) + ldc);             \
    const float* src = B + (size_t)(bn + ldr) * K + (k0) + ldc;                \
    pb[0] = *(const f32x4*)src;                                                \
    pb[1] = *(const f32x4*)(src + 4);                                          \
  }

  GLOAD64(0);
  for (int k0 = 0; k0 < K; k0 += 32) {
    *(s16x8*)&sA[ldr][ldc] = pa;
    *(s16x8*)&sB[ldr][ldc] = cvt8(pb[0], pb[1]);
    __syncthreads();
    if (k0 + 32 < K) GLOAD64(k0 + 32);
    s16x8 af[2], bg[2];
#pragma unroll
    for (int i = 0; i < 2; ++i) af[i] = *(s16x8*)&sA[wm + i * 16 + r][q << 3];
#pragma unroll
    for (int j = 0; j < 2; ++j) bg[j] = *(s16x8*)&sB[wn + j * 16 + r][q << 3];
#pragma unroll
    for (int i = 0; i < 2; ++i)
#pragma unroll
      for (int j = 0; j < 2; ++j)
        acc[i][j] = __builtin_amdgcn_mfma_f32_16x16x32_bf16(af[i], bg[j], acc[i][j], 0, 0, 0);
    __syncthreads();
  }
#undef GLOAD64

#pragma unroll
  for (int i = 0; i < 2; ++i)
#pragma unroll
    for (int j = 0; j < 2; ++j) {
      int n = bn + wn + j * 16 + r;
#pragma unroll
      for (int e = 0; e < 4; ++e) {
        int m = bm + wm + i * 16 + (q << 2) + e;
        float v = acc[i][j][e];
        if (BIAS) v += bias[n];
        if (ACT == 1) v = 0.5f * v * (1.f + erff(v * 0.70710678118f));
        if (RES) v += res[(size_t)m * N + n];
        if (BF16OUT) ((bf16*)Cout)[(size_t)m * N + n] = __float2bfloat16(v);
        else         ((float*)Cout)[(size_t)m * N + n] = v;
      }
    }
}

// ---------------- launch ----------------
extern "C" void kernel_launch(void* const* d_in, const int* in_sizes, int n_in,
                              void* d_out, int out_size, void* d_ws, size_t ws_size,
                              hipStream_t stream) {
  const int*   x_t     = (const int*)d_in[0];
  const int*   t       = (const int*)d_in[1];
  const float* tok_emb = (const float*)d_in[2];
  const float* tmlp_w1 = (const float*)d_in[3];
  const float* tmlp_b1 = (const float*)d_in[4];
  const float* tmlp_w2 = (const float*)d_in[5];
  const float* tmlp_b2 = (const float*)d_in[6];
  const float* ln1_g   = (const float*)d_in[7];
  const float* ln1_b   = (const float*)d_in[8];
  const float* in_w    = (const float*)d_in[9];
  const float* conv_w  = (const float*)d_in[10];
  const float* dt_w    = (const float*)d_in[11];
  const float* dt_b    = (const float*)d_in[12];
  const float* D_p     = (const float*)d_in[13];
  const float* out_w   = (const float*)d_in[14];
  const float* ln2_g   = (const float*)d_in[15];
  const float* ln2_b   = (const float*)d_in[16];
  const float* mlp_w1  = (const float*)d_in[17];
  const float* mlp_b1  = (const float*)d_in[18];
  const float* mlp_w2  = (const float*)d_in[19];
  const float* mlp_b2  = (const float*)d_in[20];
  const float* lno_g   = (const float*)d_in[21];
  const float* lno_b   = (const float*)d_in[22];
  const float* head_w  = (const float*)d_in[23];
  const float* head_b  = (const float*)d_in[24];

  char* w = (char*)d_ws;
  float* te    = (float*)w;  w += 4096;
  float* h1t   = (float*)w;  w += 16384;
  float* x     = (float*)w;  w += (size_t)M_TOK * DD * 4;
  bf16*  aIn   = (bf16*)w;   w += (size_t)M_TOK * DD * 2;
  float* proj  = (float*)w;  w += (size_t)M_TOK * PW * 4;
  float* ubuf  = (float*)w;  w += (size_t)M_TOK * DD * 4;
  float* dtbuf = (float*)w;  w += (size_t)M_TOK * DD * 4;
  float* ybuf  = (float*)w;  w += (size_t)M_TOK * DD * 4;
  float* Ebuf  = (float*)w;  w += (size_t)M_TOK * DD * 4;
  float* Aprod = (float*)w;  w += (size_t)2 * NCH * NST * DD * 4;
  float* hend  = (float*)w;  w += (size_t)2 * NCH * NST * DD * 4;
  float* h0    = (float*)w;  w += (size_t)2 * NCH * NST * DD * 4;
  bf16*  gbuf  = (bf16*)proj;

  k_te1<<<512, 256, 0, stream>>>(t, tmlp_w1, tmlp_b1, h1t);
  k_te2<<<128, 256, 0, stream>>>(h1t, tmlp_w2, tmlp_b2, te);
  k_embed<<<M_TOK, 256, 0, stream>>>(x_t, tok_emb, te, x);

  for (int i = 0; i < 6; ++i) {
    const float* inw_i  = in_w   + (size_t)i * PW * DD;
    const float* cw_i   = conv_w + (size_t)i * DD * 4;
    const float* dtw_i  = dt_w   + (size_t)i * DD * RR;
    const float* dtb_i  = dt_b   + (size_t)i * DD;
    const float* dp_i   = D_p    + (size_t)i * DD;
    const float* ow_i   = out_w  + (size_t)i * DD * DD;
    const float* m1_i   = mlp_w1 + (size_t)i * DFFW * DD;
    const float* m1b_i  = mlp_b1 + (size_t)i * DFFW;
    const float* m2_i   = mlp_w2 + (size_t)i * DD * DFFW;
    const float* m2b_i  = mlp_b2 + (size_t)i * DD;

    k_layernorm<<<M_TOK, 256, 0, stream>>>(x, ln1_g + i * DD, ln1_b + i * DD, aIn);
    gemm64<0,false,false,false><<<dim3(PW / 64, M_TOK / 64), 256, 0, stream>>>(
        aIn, inw_i, nullptr, nullptr, proj, PW, DD);
    k_conv_dt<<<M_TOK * 2, 256, 0, stream>>>(proj, cw_i, dtw_i, dtb_i, ubuf, dtbuf);
    k_scan1<<<dim3(4, NCH, 2), 128, 0, stream>>>(proj, ubuf, dtbuf, ybuf, Ebuf, Aprod, hend);
    k_scan2<<<2 * NST * DD / 256, 256, 0, stream>>>(Aprod, hend, h0);
    k_scan3<<<dim3(4, NCH, 2), 128, 0, stream>>>(proj, ubuf, ybuf, Ebuf, h0, dp_i, aIn);
    gemm64<0,false,true,false><<<dim3(DD / 64, M_TOK / 64), 256, 0, stream>>>(
        aIn, ow_i, nullptr, x, x, DD, DD);
    k_layernorm<<<M_TOK, 256, 0, stream>>>(x, ln2_g + i * DD, ln2_b + i * DD, aIn);
    gemm64<1,true,false,true><<<dim3(DFFW / 64, M_TOK / 64), 256, 0, stream>>>(
        aIn, m1_i, m1b_i, nullptr, gbuf, DFFW, DD);
    gemm64<0,false,true,true><<<dim3(DD / 64, M_TOK / 64), 256, 0, stream>>>(
        gbuf, m2_i, m2b_i, x, x, DD, DFFW);
  }

  k_layernorm<<<M_TOK, 256, 0, stream>>>(x, lno_g, lno_b, aIn);
  // head: grid (M-tiles, N-tiles); SWZ gives each XCD a contiguous run of N-panels.
  // 16*391 = 6256 blocks, divisible by 8 -> bijective.
  gemm_abt<0,false,false,true,true><<<dim3(M_TOK / 128, (50000 + 127) / 128), 256, 0, stream>>>(
      aIn, head_w, head_b, nullptr, d_out, 50000, DD);
}

// Round 7
// 1160.423 us; speedup vs baseline: 4.0950x; 1.0533x over previous
//
#include <hip/hip_runtime.h>
#include <hip/hip_bf16.h>
#include <math.h>

typedef __hip_bfloat16 bf16;
typedef short s16x8 __attribute__((ext_vector_type(8)));
typedef float f32x4 __attribute__((ext_vector_type(4)));

#define M_TOK 2048
#define DD    512
#define LSEQ  1024
#define PW    1088   /* 2D + R + 2N */
#define NST   16
#define RR    32
#define DFFW  2048
#define NCH   64
#define CH    16
#define PAD   36
#define NHEAD 50000
#define NHEADP 50048  /* padded to mult of 128 */

__device__ __forceinline__ float bf2f(bf16 v) { return __bfloat162float(v); }
__device__ __forceinline__ float siluf(float x) { return x / (1.f + expf(-x)); }

__device__ __forceinline__ s16x8 cvt8(const f32x4& a, const f32x4& b) {
  s16x8 r;
  r[0] = (short)__bfloat16_as_ushort(__float2bfloat16(a[0]));
  r[1] = (short)__bfloat16_as_ushort(__float2bfloat16(a[1]));
  r[2] = (short)__bfloat16_as_ushort(__float2bfloat16(a[2]));
  r[3] = (short)__bfloat16_as_ushort(__float2bfloat16(a[3]));
  r[4] = (short)__bfloat16_as_ushort(__float2bfloat16(b[0]));
  r[5] = (short)__bfloat16_as_ushort(__float2bfloat16(b[1]));
  r[6] = (short)__bfloat16_as_ushort(__float2bfloat16(b[2]));
  r[7] = (short)__bfloat16_as_ushort(__float2bfloat16(b[3]));
  return r;
}

// async global->LDS, 16B per lane, LDS dest = base + lane*16
__device__ __forceinline__ void gload16(const bf16* g, bf16* l) {
  __builtin_amdgcn_global_load_lds((const __attribute__((address_space(1))) void*)g,
                                   (__attribute__((address_space(3))) void*)l, 16, 0, 0);
}

__constant__ float c_invn[NST] = {
  -1.f/1, -1.f/2, -1.f/3, -1.f/4, -1.f/5, -1.f/6, -1.f/7, -1.f/8,
  -1.f/9, -1.f/10, -1.f/11, -1.f/12, -1.f/13, -1.f/14, -1.f/15, -1.f/16 };

// ---------------- f32 -> bf16 weight conversion (zero-pad past n_src) ----------------
__global__ __launch_bounds__(256) void k_cvt(
    const float* __restrict__ src, bf16* __restrict__ dst, int n_src, int n_dst)
{
  for (int i = (blockIdx.x * 256 + threadIdx.x) * 8; i < n_dst; i += gridDim.x * 256 * 8) {
    s16x8 v;
    if (i + 8 <= n_src) {
      f32x4 a = *(const f32x4*)(src + i), b = *(const f32x4*)(src + i + 4);
      v = cvt8(a, b);
    } else {
      v = (s16x8){0,0,0,0,0,0,0,0};
    }
    *(s16x8*)((short*)dst + i) = v;
  }
}

// ---------------- time embedding MLP ----------------
__global__ __launch_bounds__(256) void k_te1(
    const int* __restrict__ t, const float* __restrict__ w1, const float* __restrict__ b1,
    float* __restrict__ h1)
{
  __shared__ float semb[2][512];
  int tid = threadIdx.x;
  float t0 = (float)t[0], t1 = (float)t[1];
  {
    int k = tid;
    float f = expf((float)k * (-9.210340371976184f / 255.f));
    semb[0][k]       = sinf(t0 * f);
    semb[0][k + 256] = cosf(t0 * f);
    semb[1][k]       = sinf(t1 * f);
    semb[1][k + 256] = cosf(t1 * f);
  }
  __syncthreads();
  int wave = tid >> 6, lane = tid & 63;
  int j = blockIdx.x * 4 + wave;
  const float* wr = w1 + (size_t)j * 512;
  float s0 = 0.f, s1 = 0.f;
#pragma unroll
  for (int i = 0; i < 8; ++i) {
    int k = lane + (i << 6);
    float wv = wr[k];
    s0 += wv * semb[0][k];
    s1 += wv * semb[1][k];
  }
  for (int o = 32; o; o >>= 1) { s0 += __shfl_down(s0, o); s1 += __shfl_down(s1, o); }
  if (!lane) {
    float bv = b1[j];
    h1[j]        = siluf(s0 + bv);
    h1[2048 + j] = siluf(s1 + bv);
  }
}

__global__ __launch_bounds__(256) void k_te2(
    const float* __restrict__ h1, const float* __restrict__ w2, const float* __restrict__ b2,
    float* __restrict__ te)
{
  __shared__ float sh1[2][2048];
  int tid = threadIdx.x;
  for (int idx = tid; idx < 4096; idx += 256)
    sh1[idx >> 11][idx & 2047] = h1[idx];
  __syncthreads();
  int wave = tid >> 6, lane = tid & 63;
  int d = blockIdx.x * 4 + wave;
  const float* wr = w2 + (size_t)d * 2048;
  float s0 = 0.f, s1 = 0.f;
#pragma unroll
  for (int i = 0; i < 32; ++i) {
    int k = lane + (i << 6);
    float wv = wr[k];
    s0 += wv * sh1[0][k];
    s1 += wv * sh1[1][k];
  }
  for (int o = 32; o; o >>= 1) { s0 += __shfl_down(s0, o); s1 += __shfl_down(s1, o); }
  if (!lane) {
    float bv = b2[d];
    te[d]       = s0 + bv;
    te[512 + d] = s1 + bv;
  }
}

// ---------------- token embed + time embed add ----------------
__global__ __launch_bounds__(256) void k_embed(
    const int* __restrict__ x_t, const float* __restrict__ tok,
    const float* __restrict__ te, float* __restrict__ x)
{
  int m = blockIdx.x;
  int b = m >> 10;
  int row = x_t[m];
  const float* src = tok + (size_t)row * DD;
  for (int d = threadIdx.x; d < DD; d += 256)
    x[(size_t)m * DD + d] = src[d] + te[b * DD + d];
}

// ---------------- LayerNorm ----------------
__global__ __launch_bounds__(256) void k_layernorm(
    const float* __restrict__ x, const float* __restrict__ g, const float* __restrict__ bb,
    bf16* __restrict__ out)
{
  int m = blockIdx.x;
  const float* xr = x + (size_t)m * DD;
  float2 v = ((const float2*)xr)[threadIdx.x];
  float s = v.x + v.y, ss = v.x * v.x + v.y * v.y;
  for (int o = 32; o; o >>= 1) { s += __shfl_down(s, o); ss += __shfl_down(ss, o); }
  __shared__ float ps[4], pss[4];
  int wave = threadIdx.x >> 6, lane = threadIdx.x & 63;
  if (!lane) { ps[wave] = s; pss[wave] = ss; }
  __syncthreads();
  s = ps[0] + ps[1] + ps[2] + ps[3];
  ss = pss[0] + pss[1] + pss[2] + pss[3];
  float mu = s * (1.f / DD);
  float var = ss * (1.f / DD) - mu * mu;
  float inv = rsqrtf(var + 1e-5f);
  int d = threadIdx.x * 2;
  out[(size_t)m * DD + d]     = __float2bfloat16((v.x - mu) * inv * g[d]     + bb[d]);
  out[(size_t)m * DD + d + 1] = __float2bfloat16((v.y - mu) * inv * g[d + 1] + bb[d + 1]);
}

// ---------------- conv + dt ----------------
__global__ __launch_bounds__(256) void k_conv_dt(
    const float* __restrict__ proj, const float* __restrict__ convw,
    const float* __restrict__ dtw, const float* __restrict__ dtb,
    float* __restrict__ u, float* __restrict__ dt)
{
  int m = blockIdx.x >> 1;
  int d = ((blockIdx.x & 1) << 8) + threadIdx.x;
  int b = m >> 10, l = m & 1023;
  __shared__ float dtu[RR];
  if (threadIdx.x < RR) dtu[threadIdx.x] = proj[(size_t)m * PW + 2 * DD + threadIdx.x];
  __syncthreads();
  float c = 0.f;
#pragma unroll
  for (int j = 0; j < 4; ++j) {
    int ll = l - 3 + j;
    if (ll >= 0) c += proj[(size_t)(b * LSEQ + ll) * PW + d] * convw[d * 4 + j];
  }
  u[(size_t)m * DD + d] = siluf(c);
  float s = dtb[d];
  const float* wr = dtw + (size_t)d * RR;
#pragma unroll
  for (int r = 0; r < RR; ++r) s += dtu[r] * wr[r];
  dt[(size_t)m * DD + d] = (s > 0.f) ? (s + log1pf(expf(-s))) : log1pf(expf(s));
}

// ---------------- scan passes ----------------
__global__ __launch_bounds__(128) void k_scan1(
    const float* __restrict__ proj, const float* __restrict__ u,
    const float* __restrict__ dt, float* __restrict__ yloc,
    float* __restrict__ Ebuf, float* __restrict__ Aprod, float* __restrict__ hend)
{
  int d = (blockIdx.x << 7) + threadIdx.x;
  int c = blockIdx.y, b = blockIdx.z;
  int m0 = b * LSEQ + c * CH;
  __shared__ float sBC[CH][32];
  for (int idx = threadIdx.x; idx < CH * 32; idx += 128)
    sBC[idx >> 5][idx & 31] = proj[(size_t)(m0 + (idx >> 5)) * PW + 2 * DD + RR + (idx & 31)];
  __syncthreads();
  float h[NST];
#pragma unroll
  for (int n = 0; n < NST; ++n) h[n] = 0.f;
  float S = 0.f;
  for (int l = 0; l < CH; ++l) {
    size_t m = (size_t)(m0 + l);
    float dtv = dt[m * DD + d];
    float uv  = u[m * DD + d];
    float e1 = expf(-dtv);
    S += dtv;
    Ebuf[m * DD + d] = expf(-S);
    float p = 1.f, acc = 0.f;
#pragma unroll
    for (int n = 0; n < NST; ++n) {
      p *= e1;
      float bu = (p - 1.f) * c_invn[n] * sBC[l][n] * uv;
      h[n] = p * h[n] + bu;
      acc += sBC[l][16 + n] * h[n];
    }
    yloc[m * DD + d] = acc;
  }
  float Ec = expf(-S);
  float p = 1.f;
  size_t base = ((size_t)(b * NCH + c) * NST) * DD + d;
#pragma unroll
  for (int n = 0; n < NST; ++n) {
    p *= Ec;
    Aprod[base + (size_t)n * DD] = p;
    hend [base + (size_t)n * DD] = h[n];
  }
}

__global__ __launch_bounds__(256) void k_scan2(
    const float* __restrict__ Aprod, const float* __restrict__ hend, float* __restrict__ h0)
{
  int idx = blockIdx.x * 256 + threadIdx.x;
  int d = idx & 511;
  int n = (idx >> 9) & 15;
  int b = idx >> 13;
  float h = 0.f;
  for (int c = 0; c < NCH; ++c) {
    size_t o = ((size_t)((b * NCH + c) * NST + n)) * DD + d;
    h0[o] = h;
    h = Aprod[o] * h + hend[o];
  }
}

__global__ __launch_bounds__(128) void k_scan3(
    const float* __restrict__ proj, const float* __restrict__ u,
    const float* __restrict__ yloc, const float* __restrict__ Ebuf,
    const float* __restrict__ h0, const float* __restrict__ Dp, bf16* __restrict__ out)
{
  int d = (blockIdx.x << 7) + threadIdx.x;
  int c = blockIdx.y, b = blockIdx.z;
  int m0 = b * LSEQ + c * CH;
  __shared__ float sC[CH][NST];
  for (int idx = threadIdx.x; idx < CH * NST; idx += 128)
    sC[idx >> 4][idx & 15] = proj[(size_t)(m0 + (idx >> 4)) * PW + 2 * DD + RR + NST + (idx & 15)];
  __syncthreads();
  float hh[NST];
  size_t base = ((size_t)(b * NCH + c) * NST) * DD + d;
#pragma unroll
  for (int n = 0; n < NST; ++n) hh[n] = h0[base + (size_t)n * DD];
  float dpv = Dp[d];
  for (int l = 0; l < CH; ++l) {
    size_t m = (size_t)(m0 + l);
    float E = Ebuf[m * DD + d];
    float p = 1.f, corr = 0.f;
#pragma unroll
    for (int n = 0; n < NST; ++n) {
      p *= E;
      corr += sC[l][n] * p * hh[n];
    }
    float y = yloc[m * DD + d] + corr;
    float z = proj[m * PW + DD + d];
    float v = (y + u[m * DD + d] * dpv) * siluf(z);
    out[m * DD + d] = __float2bfloat16(v);
  }
}

// ================= bf16xbf16 GEMMs with global_load_lds (m97 structure) =================
// C[m,n] = sum_k A[m,k]*B[n,k]; A,B bf16 row-major, K mult of 32.
// Grid: (M-tiles, N-tiles); bijective XCD swizzle (grid total must be %8==0).
template<int ACT, bool BF16OUT, bool RES, bool BIAS>
__global__ __launch_bounds__(256) void gemm_bb128(
    const bf16* __restrict__ A, const bf16* __restrict__ B,
    const float* __restrict__ bias, const float* __restrict__ res,
    void* __restrict__ Cout, int N, int K)
{
  __shared__ bf16 sA[128 * 32];
  __shared__ bf16 sB[128 * 32];
  int flat = blockIdx.y * gridDim.x + blockIdx.x;
  int qq = (gridDim.x * gridDim.y) >> 3;
  int s = (flat & 7) * qq + (flat >> 3);
  int bm = (s % gridDim.x) * 128;
  int bn = (s / gridDim.x) * 128;
  int tid = threadIdx.x;
  int wave = tid >> 6, lane = tid & 63;
  int wm = (wave >> 1) << 6, wn = (wave & 1) << 6;
  int r = lane & 15, q = lane >> 4;
  int srow = (wave << 4) + (lane >> 2);     // 0..63
  int scol = (lane & 3) << 3;
  const bf16* pA = A + (size_t)(bm + srow) * K + scol;
  const bf16* pB = B + (size_t)(bn + srow) * K + scol;
  bf16* lA = sA + ((wave << 4) << 5);       // wave-uniform LDS base
  bf16* lB = sB + ((wave << 4) << 5);

  f32x4 acc[4][4];
#pragma unroll
  for (int i = 0; i < 4; ++i)
#pragma unroll
    for (int j = 0; j < 4; ++j) acc[i][j] = (f32x4){0.f, 0.f, 0.f, 0.f};

  for (int k0 = 0; k0 < K; k0 += 32) {
    gload16(pA,                  lA);
    gload16(pA + (size_t)64 * K, lA + 64 * 32);
    gload16(pB,                  lB);
    gload16(pB + (size_t)64 * K, lB + 64 * 32);
    pA += 32; pB += 32;
    __syncthreads();
    s16x8 af[4], bg[4];
#pragma unroll
    for (int i = 0; i < 4; ++i) af[i] = *(s16x8*)&sA[((wm + i * 16 + r) << 5) + (q << 3)];
#pragma unroll
    for (int j = 0; j < 4; ++j) bg[j] = *(s16x8*)&sB[((wn + j * 16 + r) << 5) + (q << 3)];
#pragma unroll
    for (int i = 0; i < 4; ++i)
#pragma unroll
      for (int j = 0; j < 4; ++j)
        acc[i][j] = __builtin_amdgcn_mfma_f32_16x16x32_bf16(af[i], bg[j], acc[i][j], 0, 0, 0);
    __syncthreads();
  }

#pragma unroll
  for (int i = 0; i < 4; ++i)
#pragma unroll
    for (int j = 0; j < 4; ++j) {
      int n = bn + wn + j * 16 + r;
      if (n >= N) continue;
#pragma unroll
      for (int e = 0; e < 4; ++e) {
        int m = bm + wm + i * 16 + (q << 2) + e;
        float v = acc[i][j][e];
        if (BIAS) v += bias[n];
        if (ACT == 1) v = 0.5f * v * (1.f + erff(v * 0.70710678118f));
        if (RES) v += res[(size_t)m * N + n];
        if (BF16OUT) ((bf16*)Cout)[(size_t)m * N + n] = __float2bfloat16(v);
        else         ((float*)Cout)[(size_t)m * N + n] = v;
      }
    }
}

template<int ACT, bool BF16OUT, bool RES, bool BIAS>
__global__ __launch_bounds__(256) void gemm_bb64(
    const bf16* __restrict__ A, const bf16* __restrict__ B,
    const float* __restrict__ bias, const float* __restrict__ res,
    void* __restrict__ Cout, int N, int K)
{
  __shared__ bf16 sA[64 * 32];
  __shared__ bf16 sB[64 * 32];
  int flat = blockIdx.y * gridDim.x + blockIdx.x;
  int qq = (gridDim.x * gridDim.y) >> 3;
  int s = (flat & 7) * qq + (flat >> 3);
  int bm = (s % gridDim.x) * 64;
  int bn = (s / gridDim.x) * 64;
  int tid = threadIdx.x;
  int wave = tid >> 6, lane = tid & 63;
  int wm = (wave >> 1) << 5, wn = (wave & 1) << 5;
  int r = lane & 15, q = lane >> 4;
  int srow = (wave << 4) + (lane >> 2);
  int scol = (lane & 3) << 3;
  const bf16* pA = A + (size_t)(bm + srow) * K + scol;
  const bf16* pB = B + (size_t)(bn + srow) * K + scol;
  bf16* lA = sA + ((wave << 4) << 5);
  bf16* lB = sB + ((wave << 4) << 5);

  f32x4 acc[2][2];
#pragma unroll
  for (int i = 0; i < 2; ++i)
#pragma unroll
    for (int j = 0; j < 2; ++j) acc[i][j] = (f32x4){0.f, 0.f, 0.f, 0.f};

  for (int k0 = 0; k0 < K; k0 += 32) {
    gload16(pA, lA);
    gload16(pB, lB);
    pA += 32; pB += 32;
    __syncthreads();
    s16x8 af[2], bg[2];
#pragma unroll
    for (int i = 0; i < 2; ++i) af[i] = *(s16x8*)&sA[((wm + i * 16 + r) << 5) + (q << 3)];
#pragma unroll
    for (int j = 0; j < 2; ++j) bg[j] = *(s16x8*)&sB[((wn + j * 16 + r) << 5) + (q << 3)];
#pragma unroll
    for (int i = 0; i < 2; ++i)
#pragma unroll
      for (int j = 0; j < 2; ++j)
        acc[i][j] = __builtin_amdgcn_mfma_f32_16x16x32_bf16(af[i], bg[j], acc[i][j], 0, 0, 0);
    __syncthreads();
  }

#pragma unroll
  for (int i = 0; i < 2; ++i)
#pragma unroll
    for (int j = 0; j < 2; ++j) {
      int n = bn + wn + j * 16 + r;
#pragma unroll
      for (int e = 0; e < 4; ++e) {
        int m = bm + wm + i * 16 + (q << 2) + e;
        float v = acc[i][j][e];
        if (BIAS) v += bias[n];
        if (ACT == 1) v = 0.5f * v * (1.f + erff(v * 0.70710678118f));
        if (RES) v += res[(size_t)m * N + n];
        if (BF16OUT) ((bf16*)Cout)[(size_t)m * N + n] = __float2bfloat16(v);
        else         ((float*)Cout)[(size_t)m * N + n] = v;
      }
    }
}

// ================= fallback f32-weight GEMMs (round-6 path) =================
template<int ACT, bool BF16OUT, bool RES, bool BIAS, bool SWZ>
__global__ __launch_bounds__(256) void gemm_abt(
    const bf16* __restrict__ A, const float* __restrict__ B,
    const float* __restrict__ bias, const float* __restrict__ res,
    void* __restrict__ Cout, int N, int K)
{
  __shared__ bf16 sA[128][PAD];
  __shared__ bf16 sB[128][PAD];
  int bn, bm;
  if (SWZ) {
    int flat = blockIdx.y * gridDim.x + blockIdx.x;
    int q = (gridDim.x * gridDim.y) >> 3;
    int s = (flat & 7) * q + (flat >> 3);
    bm = (s % gridDim.x) * 128;
    bn = (s / gridDim.x) * 128;
  } else {
    bn = blockIdx.x * 128;
    bm = blockIdx.y * 128;
  }
  int tid = threadIdx.x;
  int wave = tid >> 6, lane = tid & 63;
  int wm = (wave >> 1) << 6, wn = (wave & 1) << 6;
  int r = lane & 15, q = lane >> 4;
  int ldr = tid >> 2;
  int ldc = (tid & 3) << 3;
  f32x4 acc[4][4];
#pragma unroll
  for (int i = 0; i < 4; ++i)
#pragma unroll
    for (int j = 0; j < 4; ++j) acc[i][j] = (f32x4){0.f, 0.f, 0.f, 0.f};
  s16x8 pa[2];
  f32x4 pb[2][2];
#define GLOAD(k0)                                                              \
  {                                                                            \
    _Pragma("unroll")                                                          \
    for (int h = 0; h < 2; ++h) {                                              \
      int row = ldr + (h << 6);                                                \
      pa[h] = *(const s16x8*)(A + (size_t)(bm + row) * K + (k0) + ldc);        \
      int nrow = bn + row;                                                     \
      if (nrow < N) {                                                          \
        const float* src = B + (size_t)nrow * K + (k0) + ldc;                  \
        pb[h][0] = *(const f32x4*)src;                                         \
        pb[h][1] = *(const f32x4*)(src + 4);                                   \
      } else {                                                                 \
        pb[h][0] = (f32x4){0.f,0.f,0.f,0.f};                                   \
        pb[h][1] = (f32x4){0.f,0.f,0.f,0.f};                                   \
      }                                                                        \
    }                                                                          \
  }
  GLOAD(0);
  for (int k0 = 0; k0 < K; k0 += 32) {
#pragma unroll
    for (int h = 0; h < 2; ++h) {
      int row = ldr + (h << 6);
      *(s16x8*)&sA[row][ldc] = pa[h];
      *(s16x8*)&sB[row][ldc] = cvt8(pb[h][0], pb[h][1]);
    }
    __syncthreads();
    if (k0 + 32 < K) GLOAD(k0 + 32);
    s16x8 af[4], bg[4];
#pragma unroll
    for (int i = 0; i < 4; ++i) af[i] = *(s16x8*)&sA[wm + i * 16 + r][q << 3];
#pragma unroll
    for (int j = 0; j < 4; ++j) bg[j] = *(s16x8*)&sB[wn + j * 16 + r][q << 3];
#pragma unroll
    for (int i = 0; i < 4; ++i)
#pragma unroll
      for (int j = 0; j < 4; ++j)
        acc[i][j] = __builtin_amdgcn_mfma_f32_16x16x32_bf16(af[i], bg[j], acc[i][j], 0, 0, 0);
    __syncthreads();
  }
#undef GLOAD
#pragma unroll
  for (int i = 0; i < 4; ++i)
#pragma unroll
    for (int j = 0; j < 4; ++j) {
      int n = bn + wn + j * 16 + r;
      if (n >= N) continue;
#pragma unroll
      for (int e = 0; e < 4; ++e) {
        int m = bm + wm + i * 16 + (q << 2) + e;
        float v = acc[i][j][e];
        if (BIAS) v += bias[n];
        if (ACT == 1) v = 0.5f * v * (1.f + erff(v * 0.70710678118f));
        if (RES) v += res[(size_t)m * N + n];
        if (BF16OUT) ((bf16*)Cout)[(size_t)m * N + n] = __float2bfloat16(v);
        else         ((float*)Cout)[(size_t)m * N + n] = v;
      }
    }
}

template<int ACT, bool BF16OUT, bool RES, bool BIAS>
__global__ __launch_bounds__(256) void gemm64(
    const bf16* __restrict__ A, const float* __restrict__ B,
    const float* __restrict__ bias, const float* __restrict__ res,
    void* __restrict__ Cout, int N, int K)
{
  __shared__ bf16 sA[64][PAD];
  __shared__ bf16 sB[64][PAD];
  int bn = blockIdx.x * 64;
  int bm = blockIdx.y * 64;
  int tid = threadIdx.x;
  int wave = tid >> 6, lane = tid & 63;
  int wm = (wave >> 1) << 5, wn = (wave & 1) << 5;
  int r = lane & 15, q = lane >> 4;
  int ldr = tid >> 2;
  int ldc = (tid & 3) << 3;
  f32x4 acc[2][2];
#pragma unroll
  for (int i = 0; i < 2; ++i)
#pragma unroll
    for (int j = 0; j < 2; ++j) acc[i][j] = (f32x4){0.f, 0.f, 0.f, 0.f};
  s16x8 pa;
  f32x4 pb[2];
#define GLOAD64(k0)                                                            \
  {                                                                            \
    pa = *(const s16x8*)(A + (size_t)(bm + ldr) * K + (k0) + ldc);             \
    const float* src = B + (size_t)(bn + ldr) * K + (k0) + ldc;                \
    pb[0] = *(const f32x4*)src;                                                \
    pb[1] = *(const f32x4*)(src + 4);                                          \
  }
  GLOAD64(0);
  for (int k0 = 0; k0 < K; k0 += 32) {
    *(s16x8*)&sA[ldr][ldc] = pa;
    *(s16x8*)&sB[ldr][ldc] = cvt8(pb[0], pb[1]);
    __syncthreads();
    if (k0 + 32 < K) GLOAD64(k0 + 32);
    s16x8 af[2], bg[2];
#pragma unroll
    for (int i = 0; i < 2; ++i) af[i] = *(s16x8*)&sA[wm + i * 16 + r][q << 3];
#pragma unroll
    for (int j = 0; j < 2; ++j) bg[j] = *(s16x8*)&sB[wn + j * 16 + r][q << 3];
#pragma unroll
    for (int i = 0; i < 2; ++i)
#pragma unroll
      for (int j = 0; j < 2; ++j)
        acc[i][j] = __builtin_amdgcn_mfma_f32_16x16x32_bf16(af[i], bg[j], acc[i][j], 0, 0, 0);
    __syncthreads();
  }
#undef GLOAD64
#pragma unroll
  for (int i = 0; i < 2; ++i)
#pragma unroll
    for (int j = 0; j < 2; ++j) {
      int n = bn + wn + j * 16 + r;
#pragma unroll
      for (int e = 0; e < 4; ++e) {
        int m = bm + wm + i * 16 + (q << 2) + e;
        float v = acc[i][j][e];
        if (BIAS) v += bias[n];
        if (ACT == 1) v = 0.5f * v * (1.f + erff(v * 0.70710678118f));
        if (RES) v += res[(size_t)m * N + n];
        if (BF16OUT) ((bf16*)Cout)[(size_t)m * N + n] = __float2bfloat16(v);
        else         ((float*)Cout)[(size_t)m * N + n] = v;
      }
    }
}

// ---------------- launch ----------------
extern "C" void kernel_launch(void* const* d_in, const int* in_sizes, int n_in,
                              void* d_out, int out_size, void* d_ws, size_t ws_size,
                              hipStream_t stream) {
  const int*   x_t     = (const int*)d_in[0];
  const int*   t       = (const int*)d_in[1];
  const float* tok_emb = (const float*)d_in[2];
  const float* tmlp_w1 = (const float*)d_in[3];
  const float* tmlp_b1 = (const float*)d_in[4];
  const float* tmlp_w2 = (const float*)d_in[5];
  const float* tmlp_b2 = (const float*)d_in[6];
  const float* ln1_g   = (const float*)d_in[7];
  const float* ln1_b   = (const float*)d_in[8];
  const float* in_w    = (const float*)d_in[9];
  const float* conv_w  = (const float*)d_in[10];
  const float* dt_w    = (const float*)d_in[11];
  const float* dt_b    = (const float*)d_in[12];
  const float* D_p     = (const float*)d_in[13];
  const float* out_w   = (const float*)d_in[14];
  const float* ln2_g   = (const float*)d_in[15];
  const float* ln2_b   = (const float*)d_in[16];
  const float* mlp_w1  = (const float*)d_in[17];
  const float* mlp_b1  = (const float*)d_in[18];
  const float* mlp_w2  = (const float*)d_in[19];
  const float* mlp_b2  = (const float*)d_in[20];
  const float* lno_g   = (const float*)d_in[21];
  const float* lno_b   = (const float*)d_in[22];
  const float* head_w  = (const float*)d_in[23];
  const float* head_b  = (const float*)d_in[24];

  char* w = (char*)d_ws;
  float* te    = (float*)w;  w += 4096;
  float* h1t   = (float*)w;  w += 16384;
  float* x     = (float*)w;  w += (size_t)M_TOK * DD * 4;
  bf16*  aIn   = (bf16*)w;   w += (size_t)M_TOK * DD * 2;
  float* proj  = (float*)w;  w += (size_t)M_TOK * PW * 4;
  float* ubuf  = (float*)w;  w += (size_t)M_TOK * DD * 4;
  float* dtbuf = (float*)w;  w += (size_t)M_TOK * DD * 4;
  float* ybuf  = (float*)w;  w += (size_t)M_TOK * DD * 4;
  float* Ebuf  = (float*)w;  w += (size_t)M_TOK * DD * 4;
  float* Aprod = (float*)w;  w += (size_t)2 * NCH * NST * DD * 4;
  float* hend  = (float*)w;  w += (size_t)2 * NCH * NST * DD * 4;
  float* h0    = (float*)w;  w += (size_t)2 * NCH * NST * DD * 4;
  bf16*  gbuf  = (bf16*)proj;
  // bf16 weight pool (new path)
  bf16* bw_in   = (bf16*)w;  w += (size_t)6 * PW * DD * 2;
  bf16* bw_out  = (bf16*)w;  w += (size_t)6 * DD * DD * 2;
  bf16* bw_m1   = (bf16*)w;  w += (size_t)6 * DFFW * DD * 2;
  bf16* bw_m2   = (bf16*)w;  w += (size_t)6 * DD * DFFW * 2;
  bf16* bw_head = (bf16*)w;  w += (size_t)NHEADP * DD * 2;
  bool fast = ((size_t)(w - (char*)d_ws) <= ws_size);

  if (fast) {
    k_cvt<<<1024, 256, 0, stream>>>(in_w,   bw_in,   6 * PW * DD,   6 * PW * DD);
    k_cvt<<<1024, 256, 0, stream>>>(out_w,  bw_out,  6 * DD * DD,   6 * DD * DD);
    k_cvt<<<1024, 256, 0, stream>>>(mlp_w1, bw_m1,   6 * DFFW * DD, 6 * DFFW * DD);
    k_cvt<<<1024, 256, 0, stream>>>(mlp_w2, bw_m2,   6 * DD * DFFW, 6 * DD * DFFW);
    k_cvt<<<2048, 256, 0, stream>>>(head_w, bw_head, NHEAD * DD,    NHEADP * DD);
  }

  k_te1<<<512, 256, 0, stream>>>(t, tmlp_w1, tmlp_b1, h1t);
  k_te2<<<128, 256, 0, stream>>>(h1t, tmlp_w2, tmlp_b2, te);
  k_embed<<<M_TOK, 256, 0, stream>>>(x_t, tok_emb, te, x);

  for (int i = 0; i < 6; ++i) {
    const float* cw_i   = conv_w + (size_t)i * DD * 4;
    const float* dtw_i  = dt_w   + (size_t)i * DD * RR;
    const float* dtb_i  = dt_b   + (size_t)i * DD;
    const float* dp_i   = D_p    + (size_t)i * DD;
    const float* m1b_i  = mlp_b1 + (size_t)i * DFFW;
    const float* m2b_i  = mlp_b2 + (size_t)i * DD;

    k_layernorm<<<M_TOK, 256, 0, stream>>>(x, ln1_g + i * DD, ln1_b + i * DD, aIn);
    if (fast)
      gemm_bb64<0,false,false,false><<<dim3(M_TOK / 64, PW / 64), 256, 0, stream>>>(
          aIn, bw_in + (size_t)i * PW * DD, nullptr, nullptr, proj, PW, DD);
    else
      gemm64<0,false,false,false><<<dim3(PW / 64, M_TOK / 64), 256, 0, stream>>>(
          aIn, in_w + (size_t)i * PW * DD, nullptr, nullptr, proj, PW, DD);
    k_conv_dt<<<M_TOK * 2, 256, 0, stream>>>(proj, cw_i, dtw_i, dtb_i, ubuf, dtbuf);
    k_scan1<<<dim3(4, NCH, 2), 128, 0, stream>>>(proj, ubuf, dtbuf, ybuf, Ebuf, Aprod, hend);
    k_scan2<<<2 * NST * DD / 256, 256, 0, stream>>>(Aprod, hend, h0);
    k_scan3<<<dim3(4, NCH, 2), 128, 0, stream>>>(proj, ubuf, ybuf, Ebuf, h0, dp_i, aIn);
    if (fast) {
      gemm_bb64<0,false,true,false><<<dim3(M_TOK / 64, DD / 64), 256, 0, stream>>>(
          aIn, bw_out + (size_t)i * DD * DD, nullptr, x, x, DD, DD);
      k_layernorm<<<M_TOK, 256, 0, stream>>>(x, ln2_g + i * DD, ln2_b + i * DD, aIn);
      gemm_bb128<1,true,false,true><<<dim3(M_TOK / 128, DFFW / 128), 256, 0, stream>>>(
          aIn, bw_m1 + (size_t)i * DFFW * DD, m1b_i, nullptr, gbuf, DFFW, DD);
      gemm_bb64<0,false,true,true><<<dim3(M_TOK / 64, DD / 64), 256, 0, stream>>>(
          gbuf, bw_m2 + (size_t)i * DD * DFFW, m2b_i, x, x, DD, DFFW);
    } else {
      gemm64<0,false,true,false><<<dim3(DD / 64, M_TOK / 64), 256, 0, stream>>>(
          aIn, out_w + (size_t)i * DD * DD, nullptr, x, x, DD, DD);
      k_layernorm<<<M_TOK, 256, 0, stream>>>(x, ln2_g + i * DD, ln2_b + i * DD, aIn);
      gemm64<1,true,false,true><<<dim3(DFFW / 64, M_TOK / 64), 256, 0, stream>>>(
          aIn, mlp_w1 + (size_t)i * DFFW * DD, m1b_i, nullptr, gbuf, DFFW, DD);
      gemm64<0,false,true,true><<<dim3(DD / 64, M_TOK / 64), 256, 0, stream>>>(
          gbuf, mlp_w2 + (size_t)i * DD * DFFW, m2b_i, x, x, DD, DFFW);
    }
  }

  k_layernorm<<<M_TOK, 256, 0, stream>>>(x, lno_g, lno_b, aIn);
  if (fast)
    gemm_bb128<0,false,false,true><<<dim3(M_TOK / 128, NHEADP / 128), 256, 0, stream>>>(
        aIn, bw_head, head_b, nullptr, d_out, NHEAD, DD);
  else
    gemm_abt<0,false,false,true,true><<<dim3(M_TOK / 128, (NHEAD + 127) / 128), 256, 0, stream>>>(
        aIn, head_w, head_b, nullptr, d_out, NHEAD, DD);
}